// Round 9
// baseline (274.025 us; speedup 1.0000x reference)
//
#include <hip/hip_runtime.h>

// GraphSAGE 2-layer + link predictor.
// CSR via 2-level bucket sort -> xcast (chunk-major) -> gatherc<0> (xa agg planes)
// -> fused_gemm (h1 in LDS; g/r planes out) -> gatherc<1> (h2 row-major) -> linkpred.
// Gather: 4 feature-chunks of 16 feats, chunk-major planes, blockIdx%8 -> XCD pinning
// so each XCD's 3.2MB chunk slice is L2-resident. Lane-per-node serial edge loop.

typedef __attribute__((ext_vector_type(8))) short bf16x8;
typedef __attribute__((ext_vector_type(4))) float f32x4;

#define NBLK_A 256   // blocks in edge-chunk passes

__device__ __forceinline__ unsigned short f2bf(float f) {
    unsigned u = __float_as_uint(f);
    u = u + 0x7fffu + ((u >> 16) & 1u);   // RTNE
    return (unsigned short)(u >> 16);
}
__device__ __forceinline__ float b2f(unsigned short s) {
    return __uint_as_float(((unsigned)s) << 16);
}
__device__ __forceinline__ float uflo(unsigned v) { return __uint_as_float(v << 16); }
__device__ __forceinline__ float ufhi(unsigned v) { return __uint_as_float(v & 0xffff0000u); }
__device__ __forceinline__ unsigned pk2(float a, float b) {
    return (unsigned)f2bf(a) | ((unsigned)f2bf(b) << 16);
}

__device__ __forceinline__ long load_idx(const void* p, long i, int is64) {
    if (is64) return (long)((const long long*)p)[i];
    return (long)((const int*)p)[i];
}

__global__ void detect64_kernel(const void* eidx, int* flag) {
    const unsigned* u = (const unsigned*)eidx;
    unsigned acc = 0;
    for (int i = 0; i < 128; ++i) acc |= u[2 * i + 1];
    *flag = (acc == 0u) ? 1 : 0;
}

// Pass A: per-block LDS histogram of dst>>8. blk_hist is bucket-major [NBK][NBLK_A].
__global__ void bucket_count_kernel(const void* eidx, const int* flag,
                                    int* __restrict__ blk_hist, long E, int NBK, int chunk) {
    __shared__ int h[512];          // NBK <= 512 (N <= 131072)
    int tid = threadIdx.x, b = blockIdx.x;
    for (int i = tid; i < NBK; i += 256) h[i] = 0;
    __syncthreads();
    int is64 = *flag;
    long e0 = (long)b * chunk;
    long e1 = e0 + chunk; if (e1 > E) e1 = E;
    for (long e = e0 + tid; e < e1; e += 256) {
        long dst = load_idx(eidx, E + e, is64);
        atomicAdd(&h[(int)(dst >> 8)], 1);
    }
    __syncthreads();
    for (int i = tid; i < NBK; i += 256) blk_hist[i * NBLK_A + b] = h[i];
}

// Pass B1: total[k] = sum_b blk_hist[k][b]
__global__ void bucket_total_kernel(const int* __restrict__ blk_hist, int* __restrict__ total) {
    __shared__ int ts[256];
    int k = blockIdx.x, t = threadIdx.x;
    ts[t] = blk_hist[k * NBLK_A + t];
    __syncthreads();
    for (int off = 128; off > 0; off >>= 1) {
        if (t < off) ts[t] += ts[t + off];
        __syncthreads();
    }
    if (t == 0) total[k] = ts[0];
}

// Pass B2: exclusive scan of bucket totals; also row_start[N] = E.
__global__ void bucket_base_kernel(const int* __restrict__ total, int* __restrict__ base,
                                   int* __restrict__ row_start, int NBK, long N, long E) {
    int acc = 0;
    for (int k = 0; k < NBK; ++k) { base[k] = acc; acc += total[k]; }
    base[NBK] = acc;
    row_start[N] = (int)E;
}

// Pass B3: blk_hist[k][b] <- base[k] + exclusive_scan_b(blk_hist[k][:])
__global__ void bucket_off_kernel(int* __restrict__ blk_hist, const int* __restrict__ base) {
    __shared__ int ts[256];
    int k = blockIdx.x, t = threadIdx.x;
    int v = blk_hist[k * NBLK_A + t];
    ts[t] = v; __syncthreads();
    for (int off = 1; off < 256; off <<= 1) {
        int u = (t >= off) ? ts[t - off] : 0;
        __syncthreads();
        ts[t] += u;
        __syncthreads();
    }
    blk_hist[k * NBLK_A + t] = base[k] + ts[t] - v;
}

// Pass C: scatter packed (dst_local<<24 | src) into bucket-contiguous regions.
__global__ void bucket_scatter_kernel(const void* eidx, const int* flag,
                                      const int* __restrict__ blk_hist,
                                      unsigned* __restrict__ ebuf, long E, int NBK, int chunk) {
    __shared__ int cur[512];
    int tid = threadIdx.x, b = blockIdx.x;
    for (int i = tid; i < NBK; i += 256) cur[i] = blk_hist[i * NBLK_A + b];
    __syncthreads();
    int is64 = *flag;
    long e0 = (long)b * chunk;
    long e1 = e0 + chunk; if (e1 > E) e1 = E;
    for (long e = e0 + tid; e < e1; e += 256) {
        long src = load_idx(eidx, e, is64);
        long dst = load_idx(eidx, E + e, is64);
        int pos = atomicAdd(&cur[(int)(dst >> 8)], 1);
        ebuf[pos] = (unsigned)src | ((unsigned)(dst & 255) << 24);  // src < 2^24
    }
}

// Pass D: per-bucket counting sort in LDS -> coalesced row_start + L2-local csr writes.
__global__ void bucket_csr_kernel(const unsigned* __restrict__ ebuf, const int* __restrict__ base,
                                  int* __restrict__ csr_src, int* __restrict__ row_start, long N) {
    __shared__ int cnt[256], sc[256], cur[256];
    int k = blockIdx.x, t = threadIdx.x;
    int bstart = base[k], bend = base[k + 1];
    cnt[t] = 0;
    __syncthreads();
    for (int i = bstart + t; i < bend; i += 256)
        atomicAdd(&cnt[ebuf[i] >> 24], 1);
    __syncthreads();
    int c = cnt[t];
    sc[t] = c; __syncthreads();
    for (int off = 1; off < 256; off <<= 1) {
        int u = (t >= off) ? sc[t - off] : 0;
        __syncthreads();
        sc[t] += u;
        __syncthreads();
    }
    int loff = sc[t] - c;
    cur[t] = loff;
    long n = (long)k * 256 + t;
    if (n < N) row_start[n] = bstart + loff;
    __syncthreads();
    for (int i = bstart + t; i < bend; i += 256) {
        unsigned v = ebuf[i];
        int dl = (int)(v >> 24);
        int p = atomicAdd(&cur[dl], 1);
        csr_src[bstart + p] = (int)(v & 0xFFFFFFu);
    }
}

// x (f32) -> chunk-major bf16 planes: xaow[c][n][16], c = f/16.
// Block: 32 nodes staged in LDS, 256 thr = 32 nodes x 8 (chunk,half) groups.
__global__ void xcast_kernel(const float* __restrict__ x, unsigned short* __restrict__ xaow,
                             long N, long NP) {
    __shared__ float xs[32 * 64];
    long base = (long)blockIdx.x * 32;
    int tid = threadIdx.x;
    for (int i = tid; i < 2048; i += 256) {
        long n = base + (i >> 6);
        xs[i] = (n < N) ? x[base * 64 + i] : 0.f;
    }
    __syncthreads();
    int grp = tid >> 5;          // 0..7
    int nl = tid & 31;
    int c = grp >> 1, half = grp & 1;
    long n = base + nl;
    if (n >= N) return;
    const float* p = &xs[nl * 64 + c * 16 + half * 8];
    uint4 o;
    o.x = pk2(p[0], p[1]); o.y = pk2(p[2], p[3]);
    o.z = pk2(p[4], p[5]); o.w = pk2(p[6], p[7]);
    *(uint4*)&xaow[((size_t)c * NP + n) * 16 + half * 8] = o;
}

// ---------------- chunked, XCD-pinned gather ----------------
// blockIdx = nb*8 + x; chunk c = x&3 (16 feats), node-half sub = x>>2.
// Lane owns one node: serial edge loop, 2 edges/iter, 2x uint4 per edge-chunk.
// MODE 0: xaag[c][n][16] = mean_nbr xaow[c][src][16]
// MODE 1: h2[n][c*16..] = mean_nbr grg[c][src][16] + grr[c][n][16]
#define ACC8(R, F0, F1, F2, F3, F4, F5, F6, F7) \
    F0 += uflo(R.x); F1 += ufhi(R.x); F2 += uflo(R.y); F3 += ufhi(R.y); \
    F4 += uflo(R.z); F5 += ufhi(R.z); F6 += uflo(R.w); F7 += ufhi(R.w);

template <int MODE>
__global__ void gatherc_kernel(const int* __restrict__ rs, const int* __restrict__ csr,
                               const unsigned short* __restrict__ srcP,
                               const unsigned short* __restrict__ selfP,
                               unsigned short* __restrict__ out, long N, long NP) {
    int b = blockIdx.x;
    int c = b & 3, sub = (b >> 2) & 1;
    long n = (long)(b >> 3) * 512 + sub * 256 + threadIdx.x;
    if (n >= N) return;
    const unsigned short* src = srcP + (size_t)c * NP * 16;
    int s = rs[n], e = rs[n + 1];
    uint4 sva, svb;
    if (MODE == 1) {
        const unsigned short* sp = selfP + ((size_t)c * NP + n) * 16;
        sva = *(const uint4*)sp;
        svb = *(const uint4*)(sp + 8);
    }
    float f0 = 0.f, f1 = 0.f, f2 = 0.f, f3 = 0.f, f4 = 0.f, f5 = 0.f, f6 = 0.f, f7 = 0.f;
    float g0 = 0.f, g1 = 0.f, g2 = 0.f, g3 = 0.f, g4 = 0.f, g5 = 0.f, g6 = 0.f, g7 = 0.f;
    int j = s;
    for (; j + 2 <= e; j += 2) {
        int i0 = csr[j], i1 = csr[j + 1];
        const unsigned short* p0 = src + (size_t)i0 * 16;
        const unsigned short* p1 = src + (size_t)i1 * 16;
        uint4 r0a = *(const uint4*)p0, r0b = *(const uint4*)(p0 + 8);
        uint4 r1a = *(const uint4*)p1, r1b = *(const uint4*)(p1 + 8);
        ACC8(r0a, f0, f1, f2, f3, f4, f5, f6, f7)
        ACC8(r0b, g0, g1, g2, g3, g4, g5, g6, g7)
        ACC8(r1a, f0, f1, f2, f3, f4, f5, f6, f7)
        ACC8(r1b, g0, g1, g2, g3, g4, g5, g6, g7)
    }
    if (j < e) {
        int i0 = csr[j];
        const unsigned short* p0 = src + (size_t)i0 * 16;
        uint4 r0a = *(const uint4*)p0, r0b = *(const uint4*)(p0 + 8);
        ACC8(r0a, f0, f1, f2, f3, f4, f5, f6, f7)
        ACC8(r0b, g0, g1, g2, g3, g4, g5, g6, g7)
    }
    float inv = 1.0f / fmaxf((float)(e - s), 1.0f);
    f0 *= inv; f1 *= inv; f2 *= inv; f3 *= inv;
    f4 *= inv; f5 *= inv; f6 *= inv; f7 *= inv;
    g0 *= inv; g1 *= inv; g2 *= inv; g3 *= inv;
    g4 *= inv; g5 *= inv; g6 *= inv; g7 *= inv;
    if (MODE == 1) {
        ACC8(sva, f0, f1, f2, f3, f4, f5, f6, f7)
        ACC8(svb, g0, g1, g2, g3, g4, g5, g6, g7)
    }
    uint4 oa, ob;
    oa.x = pk2(f0, f1); oa.y = pk2(f2, f3); oa.z = pk2(f4, f5); oa.w = pk2(f6, f7);
    ob.x = pk2(g0, g1); ob.y = pk2(g2, g3); ob.z = pk2(g4, g5); ob.w = pk2(g6, g7);
    unsigned short* op;
    if (MODE == 0) op = out + ((size_t)c * NP + n) * 16;
    else           op = out + (size_t)n * 64 + c * 16;
    *(uint4*)op = oa;
    *(uint4*)(op + 8) = ob;
}

// ---------------- fused MFMA GEMM: g/r planes = layer2(relu(layer1(xa))) ----------------
// A'[n][k]: k<64 -> xaag plane k/16, slot k%16 ; k>=64 -> xaow plane (k-64)/16.
// W1'[o][k] = k<64 ? W1l[o][k] : W1r[o][k-64];  W2'[o][k] = o<64 ? W2l[o][k] : W2r[o-64][k].
// Output o<64 -> grg plane o/16; o>=64 -> grr plane (o-64)/16.
__global__ __launch_bounds__(512) void fused_gemm_kernel(
        const unsigned short* __restrict__ xaag, const unsigned short* __restrict__ xaow,
        const float* __restrict__ W1l, const float* __restrict__ W1r, const float* __restrict__ b1,
        const float* __restrict__ W2l, const float* __restrict__ W2r, const float* __restrict__ b2,
        unsigned short* __restrict__ grg, unsigned short* __restrict__ grr, long N, long NP) {
    __shared__ unsigned short wbuf[128 * 128];      // 32 KB, w1 then w2
    __shared__ unsigned short h1t[8][16 * 128];     // 32 KB, per-wave h1 tile
    __shared__ float bs1[128], bs2[128];
    int tid = threadIdx.x;

    // stage W1' (k-concat of W1l|W1r, each 128x64)
    for (int i = tid; i < 16384; i += 512) {
        int o = i >> 7, k = i & 127;
        float f = (k < 64) ? W1l[o * 64 + k] : W1r[o * 64 + (k - 64)];
        wbuf[(o * 128 + k) ^ ((o & 7) << 3)] = f2bf(f);
    }
    if (tid < 128) {
        bs1[tid] = b1[tid];
        bs2[tid] = (tid < 64) ? 0.f : b2[tid - 64];
    }
    __syncthreads();

    int lane = tid & 63, wid = tid >> 6;
    int l16 = lane & 15, lg = lane >> 4;
    long n0 = (long)blockIdx.x * 128 + wid * 16;
    unsigned short* hw = h1t[wid];

    f32x4 acc[8];
#pragma unroll
    for (int ot = 0; ot < 8; ++ot) acc[ot] = (f32x4){0.f, 0.f, 0.f, 0.f};

    // ---- phase 1: h1 = relu(A' @ W1'.T + b1) ----
#pragma unroll
    for (int ks = 0; ks < 4; ++ks) {
        int k0 = ks * 32;
        int g8 = ks * 4 + lg;    // 8-feat group index 0..15
        const unsigned short* ap;
        if (g8 < 8) ap = xaag + ((size_t)(g8 >> 1) * NP + (n0 + l16)) * 16 + (g8 & 1) * 8;
        else { int h = g8 - 8; ap = xaow + ((size_t)(h >> 1) * NP + (n0 + l16)) * 16 + (h & 1) * 8; }
        bf16x8 a = *(const bf16x8*)ap;
#pragma unroll
        for (int ot = 0; ot < 8; ++ot) {
            int o = ot * 16 + l16;
            bf16x8 b = *(const bf16x8*)&wbuf[(o * 128 + k0 + 8 * lg) ^ ((o & 7) << 3)];
            acc[ot] = __builtin_amdgcn_mfma_f32_16x16x32_bf16(a, b, acc[ot], 0, 0, 0);
        }
    }
    // epilogue 1 -> own-wave LDS tile (row = node-local, col = o), swizzled
#pragma unroll
    for (int j = 0; j < 4; ++j) {
        int row = lg * 4 + j;
#pragma unroll
        for (int ot = 0; ot < 8; ++ot) {
            int col = ot * 16 + l16;
            float v = fmaxf(acc[ot][j] + bs1[col], 0.f);
            hw[(row * 128 + col) ^ ((row & 7) << 3)] = f2bf(v);
        }
    }
    __syncthreads();   // all w1 reads done
    // stage W2' (o-concat of W2l;W2r, each 64x128)
    for (int i = tid; i < 16384; i += 512) {
        int o = i >> 7, k = i & 127;
        float f = (o < 64) ? W2l[o * 128 + k] : W2r[(o - 64) * 128 + k];
        wbuf[(o * 128 + k) ^ ((o & 7) << 3)] = f2bf(f);
    }
    __syncthreads();

    // ---- phase 2: out = h1 @ W2'.T + b2' ----
#pragma unroll
    for (int ot = 0; ot < 8; ++ot) acc[ot] = (f32x4){0.f, 0.f, 0.f, 0.f};
#pragma unroll
    for (int ks = 0; ks < 4; ++ks) {
        int k0 = ks * 32;
        bf16x8 a = *(const bf16x8*)&hw[(l16 * 128 + k0 + 8 * lg) ^ ((l16 & 7) << 3)];
#pragma unroll
        for (int ot = 0; ot < 8; ++ot) {
            int o = ot * 16 + l16;
            bf16x8 b = *(const bf16x8*)&wbuf[(o * 128 + k0 + 8 * lg) ^ ((o & 7) << 3)];
            acc[ot] = __builtin_amdgcn_mfma_f32_16x16x32_bf16(a, b, acc[ot], 0, 0, 0);
        }
    }
    float bval[8];
#pragma unroll
    for (int ot = 0; ot < 8; ++ot) bval[ot] = bs2[ot * 16 + l16];
#pragma unroll
    for (int j = 0; j < 4; ++j) {
        long n = n0 + lg * 4 + j;
        if (n >= N) continue;
#pragma unroll
        for (int ot = 0; ot < 8; ++ot) {
            float v = acc[ot][j] + bval[ot];
            int o = ot * 16 + l16;
            if (ot < 4) grg[((size_t)(o >> 4) * NP + n) * 16 + (o & 15)] = f2bf(v);
            else {
                int oo = o - 64;
                grr[((size_t)(oo >> 4) * NP + n) * 16 + (oo & 15)] = f2bf(v);
            }
        }
    }
}

// linkpred: 32 lanes per pair (16 per endpoint row), shfl reduce. h2 row-major.
__global__ void linkpred_kernel(const void* pairs, const int* flag,
                                const unsigned short* __restrict__ h2,
                                const float* __restrict__ Wlp,
                                const float* __restrict__ blp,
                                float* __restrict__ out, long P) {
    long gid = (long)blockIdx.x * 512 + threadIdx.x;
    long p = gid >> 5;
    if (p >= P) return;
    int l32 = (int)(gid & 31);
    int half = l32 >> 4;     // 0: src emb, 1: dst emb
    int fq = l32 & 15;
    int is64 = *flag;
    long node = load_idx(pairs, 2 * p + half, is64);
    uint2 r = *(const uint2*)&h2[node * 64 + fq * 4];
    float4 wv = *(const float4*)&Wlp[half * 64 + fq * 4];
    float acc = uflo(r.x) * wv.x + ufhi(r.x) * wv.y + uflo(r.y) * wv.z + ufhi(r.y) * wv.w;
    acc += __shfl_xor(acc, 1, 64);
    acc += __shfl_xor(acc, 2, 64);
    acc += __shfl_xor(acc, 4, 64);
    acc += __shfl_xor(acc, 8, 64);
    acc += __shfl_xor(acc, 16, 64);
    if (l32 == 0) out[p] = 1.0f / (1.0f + expf(-(acc + blp[0])));
}

extern "C" void kernel_launch(void* const* d_in, const int* in_sizes, int n_in,
                              void* d_out, int out_size, void* d_ws, size_t ws_size,
                              hipStream_t stream) {
    const float* x    = (const float*)d_in[0];
    const void*  eidx  = d_in[1];
    const void*  pairs = d_in[2];
    const float* W1l = (const float*)d_in[3];
    const float* W1r = (const float*)d_in[4];
    const float* b1  = (const float*)d_in[5];
    const float* W2l = (const float*)d_in[6];
    const float* W2r = (const float*)d_in[7];
    const float* b2  = (const float*)d_in[8];
    const float* Wlp = (const float*)d_in[9];
    const float* blp = (const float*)d_in[10];
    float* out = (float*)d_out;

    long N = in_sizes[0] / 64;
    long E = in_sizes[1] / 2;
    long P = in_sizes[2] / 2;
    long NP = (N + 255) & ~255L;              // plane node stride
    int NBK = (int)((N + 255) >> 8);          // <= 512
    int chunk = (int)((E + NBLK_A - 1) / NBLK_A);

    char* w = (char*)d_ws;
    auto alloc = [&](size_t bytes) {
        char* p = w;
        w += (bytes + 255) & ~(size_t)255;
        return p;
    };
    int* row_start = (int*)alloc((N + 1) * sizeof(int));
    int* csr_src   = (int*)alloc(E * sizeof(int));
    int* blk_hist  = (int*)alloc((size_t)NBK * NBLK_A * sizeof(int));
    int* total     = (int*)alloc(NBK * sizeof(int));
    int* base      = (int*)alloc((NBK + 1) * sizeof(int));
    int* flag      = (int*)alloc(64);
    unsigned* ebuf = (unsigned*)alloc(E * sizeof(unsigned));
    unsigned short* xaow = (unsigned short*)alloc((size_t)NP * 64 * 2);  // 4 planes x NP x 16
    unsigned short* xaag = (unsigned short*)alloc((size_t)NP * 64 * 2);
    unsigned short* grg  = (unsigned short*)alloc((size_t)NP * 64 * 2);
    unsigned short* grr  = (unsigned short*)alloc((size_t)NP * 64 * 2);
    unsigned short* h2   = (unsigned short*)alloc((size_t)N * 64 * 2);

    detect64_kernel<<<1, 1, 0, stream>>>(eidx, flag);

    bucket_count_kernel<<<NBLK_A, 256, 0, stream>>>(eidx, flag, blk_hist, E, NBK, chunk);
    bucket_total_kernel<<<NBK, 256, 0, stream>>>(blk_hist, total);
    bucket_base_kernel<<<1, 1, 0, stream>>>(total, base, row_start, NBK, N, E);
    bucket_off_kernel<<<NBK, 256, 0, stream>>>(blk_hist, base);
    bucket_scatter_kernel<<<NBLK_A, 256, 0, stream>>>(eidx, flag, blk_hist, ebuf, E, NBK, chunk);
    bucket_csr_kernel<<<NBK, 256, 0, stream>>>(ebuf, base, csr_src, row_start, N);

    unsigned xcblocks = (unsigned)((N + 31) / 32);
    xcast_kernel<<<xcblocks, 256, 0, stream>>>(x, xaow, N, NP);

    unsigned gth_blocks = (unsigned)((N + 511) / 512) * 8;
    gatherc_kernel<0><<<gth_blocks, 256, 0, stream>>>(row_start, csr_src, xaow, (const unsigned short*)0, xaag, N, NP);

    unsigned gblocks = (unsigned)((N + 127) / 128);
    fused_gemm_kernel<<<gblocks, 512, 0, stream>>>(xaag, xaow, W1l, W1r, b1, W2l, W2r, b2, grg, grr, N, NP);

    gatherc_kernel<1><<<gth_blocks, 256, 0, stream>>>(row_start, csr_src, grg, grr, h2, N, NP);

    unsigned pblocks = (unsigned)((P * 32 + 511) / 512);
    linkpred_kernel<<<pblocks, 512, 0, stream>>>(pairs, flag, h2, Wlp, blp, out, P);
}

// Round 10
// 166.377 us; speedup vs baseline: 1.6470x; 1.6470x over previous
//
#include <hip/hip_runtime.h>

// GraphSAGE 2-layer + link predictor, layer-2 collapsed to 4 scalars/node.
// CSR via 2-level bucket sort -> xcast -> gather (xa agg half) -> wv_prep
// -> fused_gemm (h1 in per-wave LDS; ab/cd scalars out) -> sgather (UV) -> linkpred.

typedef __attribute__((ext_vector_type(8))) short bf16x8;
typedef __attribute__((ext_vector_type(4))) float f32x4;

#define NBLK_A 256   // blocks in edge-chunk passes

__device__ __forceinline__ unsigned short f2bf(float f) {
    unsigned u = __float_as_uint(f);
    u = u + 0x7fffu + ((u >> 16) & 1u);   // RTNE
    return (unsigned short)(u >> 16);
}
__device__ __forceinline__ float b2f(unsigned short s) {
    return __uint_as_float(((unsigned)s) << 16);
}
__device__ __forceinline__ float uflo(unsigned v) { return __uint_as_float(v << 16); }
__device__ __forceinline__ float ufhi(unsigned v) { return __uint_as_float(v & 0xffff0000u); }

__device__ __forceinline__ long load_idx(const void* p, long i, int is64) {
    if (is64) return (long)((const long long*)p)[i];
    return (long)((const int*)p)[i];
}

__global__ void detect64_kernel(const void* eidx, int* flag) {
    const unsigned* u = (const unsigned*)eidx;
    unsigned acc = 0;
    for (int i = 0; i < 128; ++i) acc |= u[2 * i + 1];
    *flag = (acc == 0u) ? 1 : 0;
}

// Pass A: per-block LDS histogram of dst>>8. blk_hist is bucket-major [NBK][NBLK_A].
__global__ void bucket_count_kernel(const void* eidx, const int* flag,
                                    int* __restrict__ blk_hist, long E, int NBK, int chunk) {
    __shared__ int h[512];          // NBK <= 512 (N <= 131072)
    int tid = threadIdx.x, b = blockIdx.x;
    for (int i = tid; i < NBK; i += 256) h[i] = 0;
    __syncthreads();
    int is64 = *flag;
    long e0 = (long)b * chunk;
    long e1 = e0 + chunk; if (e1 > E) e1 = E;
    for (long e = e0 + tid; e < e1; e += 256) {
        long dst = load_idx(eidx, E + e, is64);
        atomicAdd(&h[(int)(dst >> 8)], 1);
    }
    __syncthreads();
    for (int i = tid; i < NBK; i += 256) blk_hist[i * NBLK_A + b] = h[i];
}

// Pass B1: total[k] = sum_b blk_hist[k][b]
__global__ void bucket_total_kernel(const int* __restrict__ blk_hist, int* __restrict__ total) {
    __shared__ int ts[256];
    int k = blockIdx.x, t = threadIdx.x;
    ts[t] = blk_hist[k * NBLK_A + t];
    __syncthreads();
    for (int off = 128; off > 0; off >>= 1) {
        if (t < off) ts[t] += ts[t + off];
        __syncthreads();
    }
    if (t == 0) total[k] = ts[0];
}

// Pass B2: exclusive scan of bucket totals; also row_start[N] = E.
__global__ void bucket_base_kernel(const int* __restrict__ total, int* __restrict__ base,
                                   int* __restrict__ row_start, int NBK, long N, long E) {
    int acc = 0;
    for (int k = 0; k < NBK; ++k) { base[k] = acc; acc += total[k]; }
    base[NBK] = acc;
    row_start[N] = (int)E;
}

// Pass B3: blk_hist[k][b] <- base[k] + exclusive_scan_b(blk_hist[k][:])
__global__ void bucket_off_kernel(int* __restrict__ blk_hist, const int* __restrict__ base) {
    __shared__ int ts[256];
    int k = blockIdx.x, t = threadIdx.x;
    int v = blk_hist[k * NBLK_A + t];
    ts[t] = v; __syncthreads();
    for (int off = 1; off < 256; off <<= 1) {
        int u = (t >= off) ? ts[t - off] : 0;
        __syncthreads();
        ts[t] += u;
        __syncthreads();
    }
    blk_hist[k * NBLK_A + t] = base[k] + ts[t] - v;
}

// Pass C: scatter packed (dst_local<<24 | src) into bucket-contiguous regions.
__global__ void bucket_scatter_kernel(const void* eidx, const int* flag,
                                      const int* __restrict__ blk_hist,
                                      unsigned* __restrict__ ebuf, long E, int NBK, int chunk) {
    __shared__ int cur[512];
    int tid = threadIdx.x, b = blockIdx.x;
    for (int i = tid; i < NBK; i += 256) cur[i] = blk_hist[i * NBLK_A + b];
    __syncthreads();
    int is64 = *flag;
    long e0 = (long)b * chunk;
    long e1 = e0 + chunk; if (e1 > E) e1 = E;
    for (long e = e0 + tid; e < e1; e += 256) {
        long src = load_idx(eidx, e, is64);
        long dst = load_idx(eidx, E + e, is64);
        int pos = atomicAdd(&cur[(int)(dst >> 8)], 1);
        ebuf[pos] = (unsigned)src | ((unsigned)(dst & 255) << 24);  // src < 2^24
    }
}

// Pass D: per-bucket counting sort in LDS -> coalesced row_start + L2-local csr writes.
__global__ void bucket_csr_kernel(const unsigned* __restrict__ ebuf, const int* __restrict__ base,
                                  int* __restrict__ csr_src, int* __restrict__ row_start, long N) {
    __shared__ int cnt[256], sc[256], cur[256];
    int k = blockIdx.x, t = threadIdx.x;
    int bstart = base[k], bend = base[k + 1];
    cnt[t] = 0;
    __syncthreads();
    for (int i = bstart + t; i < bend; i += 256)
        atomicAdd(&cnt[ebuf[i] >> 24], 1);
    __syncthreads();
    int c = cnt[t];
    sc[t] = c; __syncthreads();
    for (int off = 1; off < 256; off <<= 1) {
        int u = (t >= off) ? sc[t - off] : 0;
        __syncthreads();
        sc[t] += u;
        __syncthreads();
    }
    int loff = sc[t] - c;
    cur[t] = loff;
    long n = (long)k * 256 + t;
    if (n < N) row_start[n] = bstart + loff;
    __syncthreads();
    for (int i = bstart + t; i < bend; i += 256) {
        unsigned v = ebuf[i];
        int dl = (int)(v >> 24);
        int p = atomicAdd(&cur[dl], 1);
        csr_src[bstart + p] = (int)(v & 0xFFFFFFu);
    }
}

// x (f32) -> xa[n][64+f] (bf16). One thread per 4 floats.
__global__ void xcast_kernel(const float* __restrict__ x, unsigned short* __restrict__ xa, long N) {
    long t = (long)blockIdx.x * 256 + threadIdx.x;
    long n = t >> 4;
    int q = (int)(t & 15);
    if (n >= N) return;
    float4 v = *(const float4*)&x[n * 64 + q * 4];
    uint2 u;
    u.x = (unsigned)f2bf(v.x) | ((unsigned)f2bf(v.y) << 16);
    u.y = (unsigned)f2bf(v.z) | ((unsigned)f2bf(v.w) << 16);
    *(uint2*)&xa[n * 128 + 64 + q * 4] = u;
}

// ---------------- gather (round-7 v3, known-good 40us) ----------------
// One wave per node. Lane l: row-group lg=l>>4, feature quad fq=l&15.
// 16 edges/iter: 4 idx loads + 4 row loads -> 16 lines in flight. Mask-free main, masked tail.
// xa[n][0:64] = mean_nbr xa[src][64:128]
__global__ void gather_kernel(const int* __restrict__ rs, const int* __restrict__ csr,
                              const unsigned short* __restrict__ T,
                              unsigned short* __restrict__ Out, long N) {
    long gid = (long)blockIdx.x * 256 + threadIdx.x;
    long n = gid >> 6;
    if (n >= N) return;
    int lane = (int)(gid & 63);
    int lg = lane >> 4;
    int fq = lane & 15;
    int s = rs[n], e = rs[n + 1];
    float a0 = 0.f, a1 = 0.f, a2 = 0.f, a3 = 0.f;
    int j = s;
    for (; j + 16 <= e; j += 16) {
        int i0 = csr[j + lg];
        int i1 = csr[j + 4 + lg];
        int i2 = csr[j + 8 + lg];
        int i3 = csr[j + 12 + lg];
        uint2 r0 = *(const uint2*)&T[(long)i0 * 128 + 64 + fq * 4];
        uint2 r1 = *(const uint2*)&T[(long)i1 * 128 + 64 + fq * 4];
        uint2 r2 = *(const uint2*)&T[(long)i2 * 128 + 64 + fq * 4];
        uint2 r3 = *(const uint2*)&T[(long)i3 * 128 + 64 + fq * 4];
        a0 += uflo(r0.x); a1 += ufhi(r0.x); a2 += uflo(r0.y); a3 += ufhi(r0.y);
        a0 += uflo(r1.x); a1 += ufhi(r1.x); a2 += uflo(r1.y); a3 += ufhi(r1.y);
        a0 += uflo(r2.x); a1 += ufhi(r2.x); a2 += uflo(r2.y); a3 += ufhi(r2.y);
        a0 += uflo(r3.x); a1 += ufhi(r3.x); a2 += uflo(r3.y); a3 += ufhi(r3.y);
    }
    if (j < e) {
#pragma unroll
        for (int t = 0; t < 4; ++t) {
            int pos = j + 4 * t + lg;
            int ok = pos < e;
            int si = csr[ok ? pos : s];          // address always in [s, e)
            uint2 r = *(const uint2*)&T[(long)si * 128 + 64 + fq * 4];
            float m = ok ? 1.f : 0.f;
            a0 += m * uflo(r.x); a1 += m * ufhi(r.x);
            a2 += m * uflo(r.y); a3 += m * ufhi(r.y);
        }
    }
    a0 += __shfl_xor(a0, 16, 64);  a1 += __shfl_xor(a1, 16, 64);
    a2 += __shfl_xor(a2, 16, 64);  a3 += __shfl_xor(a3, 16, 64);
    a0 += __shfl_xor(a0, 32, 64);  a1 += __shfl_xor(a1, 32, 64);
    a2 += __shfl_xor(a2, 32, 64);  a3 += __shfl_xor(a3, 32, 64);
    if (lg == 0) {
        float inv = 1.0f / fmaxf((float)(e - s), 1.0f);
        uint2 o;
        o.x = (unsigned)f2bf(a0 * inv) | ((unsigned)f2bf(a1 * inv) << 16);
        o.y = (unsigned)f2bf(a2 * inv) | ((unsigned)f2bf(a3 * inv) << 16);
        *(uint2*)&Out[n * 128 + fq * 4] = o;
    }
}

// ---------------- wv_prep: collapse layer2+linkpred weights ----------------
// wv[0][k]=Sum_o W2l[o][k]*wl[o], wv[1][k]=..*wr, wv[2][k]=W2r..*wl, wv[3][k]=W2r..*wr
// wv[512] = wl.b2 + wr.b2 + blp
__global__ void wv_prep_kernel(const float* __restrict__ W2l, const float* __restrict__ W2r,
                               const float* __restrict__ b2, const float* __restrict__ Wlp,
                               const float* __restrict__ blp, float* __restrict__ wv) {
    int k = threadIdx.x;   // 0..127
    float s0 = 0.f, s1 = 0.f, s2 = 0.f, s3 = 0.f;
    for (int o = 0; o < 64; ++o) {
        float wl = Wlp[o], wr = Wlp[64 + o];
        float l = W2l[o * 128 + k], r = W2r[o * 128 + k];
        s0 += wl * l; s1 += wr * l; s2 += wl * r; s3 += wr * r;
    }
    wv[k] = s0; wv[128 + k] = s1; wv[256 + k] = s2; wv[384 + k] = s3;
    if (k == 0) {
        float c = blp[0];
        for (int o = 0; o < 64; ++o) c += (Wlp[o] + Wlp[64 + o]) * b2[o];
        wv[512] = c;
    }
}

// ---------------- fused MFMA GEMM v3: ab/cd = wv . relu(layer1(xa)) ----------------
// W1'[o][k] = k<64 ? W1l[o][k] : W1r[o][k-64]    (128x128)
// 512 thr = 8 waves x 16 nodes = 128 nodes/block. h1 in per-wave LDS tile.
// Phase 2: 4 fp32 dots per node (a,b,c,d), shfl-reduced over k-quarters.
__global__ __launch_bounds__(512) void fused_gemm_kernel(
        const unsigned short* __restrict__ A,
        const float* __restrict__ W1l, const float* __restrict__ W1r, const float* __restrict__ b1,
        const float* __restrict__ wv,
        float* __restrict__ ab, float* __restrict__ cd, long N) {
    __shared__ unsigned short wbuf[128 * 128];      // 32 KB, W1'
    __shared__ unsigned short h1t[8][16 * 128];     // 32 KB, per-wave h1 tile
    __shared__ float bs1[128];
    __shared__ float wvs[512];
    int tid = threadIdx.x;

    // stage W1' (k-concat of W1l|W1r, each 128x64)
    for (int i = tid; i < 16384; i += 512) {
        int o = i >> 7, k = i & 127;
        float f = (k < 64) ? W1l[o * 64 + k] : W1r[o * 64 + (k - 64)];
        wbuf[(o * 128 + k) ^ ((o & 7) << 3)] = f2bf(f);
    }
    if (tid < 128) bs1[tid] = b1[tid];
    wvs[tid] = wv[tid];
    __syncthreads();

    int lane = tid & 63, wid = tid >> 6;
    int l16 = lane & 15, lg = lane >> 4;
    long n0 = (long)blockIdx.x * 128 + wid * 16;
    const unsigned short* A0 = A + (n0 + l16) * 128;
    unsigned short* hw = h1t[wid];

    f32x4 acc[8];
#pragma unroll
    for (int ot = 0; ot < 8; ++ot) acc[ot] = (f32x4){0.f, 0.f, 0.f, 0.f};

    // ---- phase 1: h1 = relu(xa @ W1'.T + b1) ----
#pragma unroll
    for (int ks = 0; ks < 4; ++ks) {
        int k0 = ks * 32;
        bf16x8 a = *(const bf16x8*)&A0[k0 + 8 * lg];
#pragma unroll
        for (int ot = 0; ot < 8; ++ot) {
            int o = ot * 16 + l16;
            bf16x8 b = *(const bf16x8*)&wbuf[(o * 128 + k0 + 8 * lg) ^ ((o & 7) << 3)];
            acc[ot] = __builtin_amdgcn_mfma_f32_16x16x32_bf16(a, b, acc[ot], 0, 0, 0);
        }
    }
    // epilogue 1 -> own-wave LDS tile (row = node-local, col = o), swizzled
#pragma unroll
    for (int j = 0; j < 4; ++j) {
        int row = lg * 4 + j;
#pragma unroll
        for (int ot = 0; ot < 8; ++ot) {
            int col = ot * 16 + l16;
            float v = fmaxf(acc[ot][j] + bs1[col], 0.f);
            hw[(row * 128 + col) ^ ((row & 7) << 3)] = f2bf(v);
        }
    }
    __syncthreads();

    // ---- phase 2: per-node scalars da,db,dc,dd = h1 . wv[0..3] ----
    float da = 0.f, db = 0.f, dc = 0.f, dd = 0.f;
    int nl = l16;
#pragma unroll
    for (int t = 0; t < 4; ++t) {
        bf16x8 h = *(const bf16x8*)&hw[(nl * 128 + lg * 32 + t * 8) ^ ((nl & 7) << 3)];
#pragma unroll
        for (int e2 = 0; e2 < 8; ++e2) {
            float hv = b2f((unsigned short)h[e2]);
            int k = lg * 32 + t * 8 + e2;
            da += hv * wvs[k];       db += hv * wvs[128 + k];
            dc += hv * wvs[256 + k]; dd += hv * wvs[384 + k];
        }
    }
    da += __shfl_xor(da, 16, 64); db += __shfl_xor(db, 16, 64);
    dc += __shfl_xor(dc, 16, 64); dd += __shfl_xor(dd, 16, 64);
    da += __shfl_xor(da, 32, 64); db += __shfl_xor(db, 32, 64);
    dc += __shfl_xor(dc, 32, 64); dd += __shfl_xor(dd, 32, 64);
    long n = n0 + nl;
    if (lg == 0 && n < N) {
        *(float2*)&ab[n * 2] = make_float2(da, db);
        *(float2*)&cd[n * 2] = make_float2(dc, dd);
    }
}

// ---------------- scalar gather: UV[n] = (mean_nbr a + c[n], mean_nbr b + d[n]) ----------------
__global__ void sgather_kernel(const int* __restrict__ rs, const int* __restrict__ csr,
                               const float* __restrict__ ab, const float* __restrict__ cd,
                               float* __restrict__ UV, long N) {
    long n = (long)blockIdx.x * 256 + threadIdx.x;
    if (n >= N) return;
    int s = rs[n], e = rs[n + 1];
    float sa = 0.f, sb = 0.f;
    int j = s;
    for (; j + 4 <= e; j += 4) {
        int i0 = csr[j], i1 = csr[j + 1], i2 = csr[j + 2], i3 = csr[j + 3];
        float2 v0 = *(const float2*)&ab[(long)i0 * 2];
        float2 v1 = *(const float2*)&ab[(long)i1 * 2];
        float2 v2 = *(const float2*)&ab[(long)i2 * 2];
        float2 v3 = *(const float2*)&ab[(long)i3 * 2];
        sa += (v0.x + v1.x) + (v2.x + v3.x);
        sb += (v0.y + v1.y) + (v2.y + v3.y);
    }
    for (; j < e; ++j) {
        float2 v = *(const float2*)&ab[(long)csr[j] * 2];
        sa += v.x; sb += v.y;
    }
    float inv = 1.0f / fmaxf((float)(e - s), 1.0f);
    float2 cdv = *(const float2*)&cd[n * 2];
    float2 uv = make_float2(sa * inv + cdv.x, sb * inv + cdv.y);
    *(float2*)&UV[n * 2] = uv;
}

// linkpred: out[p] = sigmoid(U[s] + V[d] + C)
__global__ void linkpred_kernel(const void* pairs, const int* flag,
                                const float* __restrict__ UV, const float* __restrict__ wv,
                                float* __restrict__ out, long P) {
    long p = (long)blockIdx.x * 256 + threadIdx.x;
    if (p >= P) return;
    int is64 = *flag;
    long s = load_idx(pairs, 2 * p, is64);
    long d = load_idx(pairs, 2 * p + 1, is64);
    float acc = UV[s * 2] + UV[d * 2 + 1] + wv[512];
    out[p] = 1.0f / (1.0f + expf(-acc));
}

extern "C" void kernel_launch(void* const* d_in, const int* in_sizes, int n_in,
                              void* d_out, int out_size, void* d_ws, size_t ws_size,
                              hipStream_t stream) {
    const float* x    = (const float*)d_in[0];
    const void*  eidx  = d_in[1];
    const void*  pairs = d_in[2];
    const float* W1l = (const float*)d_in[3];
    const float* W1r = (const float*)d_in[4];
    const float* b1  = (const float*)d_in[5];
    const float* W2l = (const float*)d_in[6];
    const float* W2r = (const float*)d_in[7];
    const float* b2  = (const float*)d_in[8];
    const float* Wlp = (const float*)d_in[9];
    const float* blp = (const float*)d_in[10];
    float* out = (float*)d_out;

    long N = in_sizes[0] / 64;
    long E = in_sizes[1] / 2;
    long P = in_sizes[2] / 2;
    long NP = (N + 127) & ~127L;
    int NBK = (int)((N + 255) >> 8);          // <= 512
    int chunk = (int)((E + NBLK_A - 1) / NBLK_A);

    char* w = (char*)d_ws;
    auto alloc = [&](size_t bytes) {
        char* p = w;
        w += (bytes + 255) & ~(size_t)255;
        return p;
    };
    int* row_start = (int*)alloc((N + 1) * sizeof(int));
    int* csr_src   = (int*)alloc(E * sizeof(int));
    int* blk_hist  = (int*)alloc((size_t)NBK * NBLK_A * sizeof(int));
    int* total     = (int*)alloc(NBK * sizeof(int));
    int* base      = (int*)alloc((NBK + 1) * sizeof(int));
    int* flag      = (int*)alloc(64);
    unsigned* ebuf = (unsigned*)alloc(E * sizeof(unsigned));
    unsigned short* xa = (unsigned short*)alloc((size_t)NP * 128 * 2);
    float* ab = (float*)alloc((size_t)N * 2 * sizeof(float));
    float* cd = (float*)alloc((size_t)N * 2 * sizeof(float));
    float* UV = (float*)alloc((size_t)N * 2 * sizeof(float));
    float* wv = (float*)alloc(1024 * sizeof(float));

    detect64_kernel<<<1, 1, 0, stream>>>(eidx, flag);

    bucket_count_kernel<<<NBLK_A, 256, 0, stream>>>(eidx, flag, blk_hist, E, NBK, chunk);
    bucket_total_kernel<<<NBK, 256, 0, stream>>>(blk_hist, total);
    bucket_base_kernel<<<1, 1, 0, stream>>>(total, base, row_start, NBK, N, E);
    bucket_off_kernel<<<NBK, 256, 0, stream>>>(blk_hist, base);
    bucket_scatter_kernel<<<NBLK_A, 256, 0, stream>>>(eidx, flag, blk_hist, ebuf, E, NBK, chunk);
    bucket_csr_kernel<<<NBK, 256, 0, stream>>>(ebuf, base, csr_src, row_start, N);

    unsigned xcblocks = (unsigned)((N * 16 + 255) / 256);
    xcast_kernel<<<xcblocks, 256, 0, stream>>>(x, xa, N);

    unsigned gth_blocks = (unsigned)((N * 64 + 255) / 256);
    gather_kernel<<<gth_blocks, 256, 0, stream>>>(row_start, csr_src, xa, xa, N);

    wv_prep_kernel<<<1, 128, 0, stream>>>(W2l, W2r, b2, Wlp, blp, wv);

    unsigned gblocks = (unsigned)(NP / 128);
    fused_gemm_kernel<<<gblocks, 512, 0, stream>>>(xa, W1l, W1r, b1, wv, ab, cd, N);

    unsigned sgblocks = (unsigned)((N + 255) / 256);
    sgather_kernel<<<sgblocks, 256, 0, stream>>>(row_start, csr_src, ab, cd, UV, N);

    unsigned pblocks = (unsigned)((P + 255) / 256);
    linkpred_kernel<<<pblocks, 256, 0, stream>>>(pairs, flag, UV, wv, out, P);
}

// Round 11
// 151.474 us; speedup vs baseline: 1.8091x; 1.0984x over previous
//
#include <hip/hip_runtime.h>

// GraphSAGE 2-layer + link predictor, layer-2 collapsed to 4 scalars/node.
// pre(count || xcast || {flag,wv,W1'bf16}) -> total -> base -> off -> scatter -> csr
// -> gather (32-bit addressing) -> fused_gemm (memcpy-staged W1') -> sgather -> linkpred.

typedef __attribute__((ext_vector_type(8))) short bf16x8;
typedef __attribute__((ext_vector_type(4))) float f32x4;

#define NBLK_A 256   // blocks in edge-chunk passes

__device__ __forceinline__ unsigned short f2bf(float f) {
    unsigned u = __float_as_uint(f);
    u = u + 0x7fffu + ((u >> 16) & 1u);   // RTNE
    return (unsigned short)(u >> 16);
}
__device__ __forceinline__ float b2f(unsigned short s) {
    return __uint_as_float(((unsigned)s) << 16);
}
__device__ __forceinline__ float uflo(unsigned v) { return __uint_as_float(v << 16); }
__device__ __forceinline__ float ufhi(unsigned v) { return __uint_as_float(v & 0xffff0000u); }

__device__ __forceinline__ long load_idx(const void* p, long i, int is64) {
    if (is64) return (long)((const long long*)p)[i];
    return (long)((const int*)p)[i];
}

__device__ __forceinline__ int detect64_local(const void* p) {
    const unsigned* u = (const unsigned*)p;
    unsigned a = 0;
#pragma unroll
    for (int i = 0; i < 32; ++i) a |= u[2 * i + 1];
    return a == 0u;
}

// ---------------- pre: bucket_count || xcast || prep ----------------
// blocks [0,NBLK_A): per-block LDS histogram of dst>>8 (local is64 detect)
// blocks [NBLK_A, NBLK_A+xcb): xcast x(f32) -> xa[n][64:128] bf16
// block NBLK_A+xcb: flag + wv collapse + W1' bf16 pre-swizzled
__global__ void pre_kernel(const void* eidx, const float* __restrict__ x,
                           const float* __restrict__ W1l, const float* __restrict__ W1r,
                           const float* __restrict__ W2l, const float* __restrict__ W2r,
                           const float* __restrict__ b2, const float* __restrict__ Wlp,
                           const float* __restrict__ blp,
                           int* __restrict__ blk_hist, unsigned short* __restrict__ xa,
                           unsigned short* __restrict__ w1bf, float* __restrict__ wv,
                           int* __restrict__ flag,
                           long N, long E, int NBK, int chunk, int xcb) {
    int b = blockIdx.x;
    int tid = threadIdx.x;
    if (b < NBLK_A) {
        __shared__ int h[512];
        for (int i = tid; i < NBK; i += 256) h[i] = 0;
        __syncthreads();
        int is64 = detect64_local(eidx);
        long e0 = (long)b * chunk;
        long e1 = e0 + chunk; if (e1 > E) e1 = E;
        for (long e = e0 + tid; e < e1; e += 256) {
            long dst = load_idx(eidx, E + e, is64);
            atomicAdd(&h[(int)(dst >> 8)], 1);
        }
        __syncthreads();
        for (int i = tid; i < NBK; i += 256) blk_hist[i * NBLK_A + b] = h[i];
    } else if (b < NBLK_A + xcb) {
        long t = (long)(b - NBLK_A) * 256 + tid;
        long n = t >> 4;
        int q = (int)(t & 15);
        if (n >= N) return;
        float4 v = *(const float4*)&x[n * 64 + q * 4];
        uint2 u;
        u.x = (unsigned)f2bf(v.x) | ((unsigned)f2bf(v.y) << 16);
        u.y = (unsigned)f2bf(v.z) | ((unsigned)f2bf(v.w) << 16);
        *(uint2*)&xa[n * 128 + 64 + q * 4] = u;
    } else {
        // prep block
        if (tid == 0) *flag = detect64_local(eidx);
        if (tid < 128) {
            int k = tid;
            float s0 = 0.f, s1 = 0.f, s2 = 0.f, s3 = 0.f;
            for (int o = 0; o < 64; ++o) {
                float wl = Wlp[o], wr = Wlp[64 + o];
                float l = W2l[o * 128 + k], r = W2r[o * 128 + k];
                s0 += wl * l; s1 += wr * l; s2 += wl * r; s3 += wr * r;
            }
            wv[k] = s0; wv[128 + k] = s1; wv[256 + k] = s2; wv[384 + k] = s3;
            if (k == 0) {
                float c = blp[0];
                for (int o = 0; o < 64; ++o) c += (Wlp[o] + Wlp[64 + o]) * b2[o];
                wv[512] = c;
            }
        }
        // W1' bf16, PRE-SWIZZLED: element (o*128+k) stored at index ^ ((o&7)<<3)
        for (int i = tid; i < 16384; i += 256) {
            int o = i >> 7, k = i & 127;
            float f = (k < 64) ? W1l[o * 64 + k] : W1r[o * 64 + (k - 64)];
            w1bf[i ^ ((o & 7) << 3)] = f2bf(f);
        }
    }
}

// Pass B1: total[k] = sum_b blk_hist[k][b]
__global__ void bucket_total_kernel(const int* __restrict__ blk_hist, int* __restrict__ total) {
    __shared__ int ts[256];
    int k = blockIdx.x, t = threadIdx.x;
    ts[t] = blk_hist[k * NBLK_A + t];
    __syncthreads();
    for (int off = 128; off > 0; off >>= 1) {
        if (t < off) ts[t] += ts[t + off];
        __syncthreads();
    }
    if (t == 0) total[k] = ts[0];
}

// Pass B2: exclusive scan of bucket totals; also row_start[N] = E.
__global__ void bucket_base_kernel(const int* __restrict__ total, int* __restrict__ base,
                                   int* __restrict__ row_start, int NBK, long N, long E) {
    int acc = 0;
    for (int k = 0; k < NBK; ++k) { base[k] = acc; acc += total[k]; }
    base[NBK] = acc;
    row_start[N] = (int)E;
}

// Pass B3: blk_hist[k][b] <- base[k] + exclusive_scan_b(blk_hist[k][:])
__global__ void bucket_off_kernel(int* __restrict__ blk_hist, const int* __restrict__ base) {
    __shared__ int ts[256];
    int k = blockIdx.x, t = threadIdx.x;
    int v = blk_hist[k * NBLK_A + t];
    ts[t] = v; __syncthreads();
    for (int off = 1; off < 256; off <<= 1) {
        int u = (t >= off) ? ts[t - off] : 0;
        __syncthreads();
        ts[t] += u;
        __syncthreads();
    }
    blk_hist[k * NBLK_A + t] = base[k] + ts[t] - v;
}

// Pass C: scatter packed (dst_local<<24 | src) into bucket-contiguous regions.
__global__ void bucket_scatter_kernel(const void* eidx, const int* flag,
                                      const int* __restrict__ blk_hist,
                                      unsigned* __restrict__ ebuf, long E, int NBK, int chunk) {
    __shared__ int cur[512];
    int tid = threadIdx.x, b = blockIdx.x;
    for (int i = tid; i < NBK; i += 256) cur[i] = blk_hist[i * NBLK_A + b];
    __syncthreads();
    int is64 = *flag;
    long e0 = (long)b * chunk;
    long e1 = e0 + chunk; if (e1 > E) e1 = E;
    for (long e = e0 + tid; e < e1; e += 256) {
        long src = load_idx(eidx, e, is64);
        long dst = load_idx(eidx, E + e, is64);
        int pos = atomicAdd(&cur[(int)(dst >> 8)], 1);
        ebuf[pos] = (unsigned)src | ((unsigned)(dst & 255) << 24);  // src < 2^24
    }
}

// Pass D: per-bucket counting sort in LDS -> coalesced row_start + L2-local csr writes.
__global__ void bucket_csr_kernel(const unsigned* __restrict__ ebuf, const int* __restrict__ base,
                                  int* __restrict__ csr_src, int* __restrict__ row_start, long N) {
    __shared__ int cnt[256], sc[256], cur[256];
    int k = blockIdx.x, t = threadIdx.x;
    int bstart = base[k], bend = base[k + 1];
    cnt[t] = 0;
    __syncthreads();
    for (int i = bstart + t; i < bend; i += 256)
        atomicAdd(&cnt[ebuf[i] >> 24], 1);
    __syncthreads();
    int c = cnt[t];
    sc[t] = c; __syncthreads();
    for (int off = 1; off < 256; off <<= 1) {
        int u = (t >= off) ? sc[t - off] : 0;
        __syncthreads();
        sc[t] += u;
        __syncthreads();
    }
    int loff = sc[t] - c;
    cur[t] = loff;
    long n = (long)k * 256 + t;
    if (n < N) row_start[n] = bstart + loff;
    __syncthreads();
    for (int i = bstart + t; i < bend; i += 256) {
        unsigned v = ebuf[i];
        int dl = (int)(v >> 24);
        int p = atomicAdd(&cur[dl], 1);
        csr_src[bstart + p] = (int)(v & 0xFFFFFFu);
    }
}

// ---------------- gather (v3 structure + 32-bit addressing) ----------------
// One wave per node. Lane l: row-group lg=l>>4, feature quad fq=l&15.
// 16 edges/iter: 4 idx loads + 4 row loads -> 16 lines in flight.
// xa[n][0:64] = mean_nbr xa[src][64:128]
__global__ void gather_kernel(const int* __restrict__ rs, const int* __restrict__ csr,
                              const unsigned short* __restrict__ T,
                              unsigned short* __restrict__ Out, long N) {
    long gid = (long)blockIdx.x * 256 + threadIdx.x;
    long n = gid >> 6;
    if (n >= N) return;
    int lane = (int)(gid & 63);
    int lg = lane >> 4;
    int fq = lane & 15;
    int s = rs[n], e = rs[n + 1];
    unsigned boff = 64u + (unsigned)fq * 4u;     // within-row element offset
    float a0 = 0.f, a1 = 0.f, a2 = 0.f, a3 = 0.f;
    int j = s;
    for (; j + 16 <= e; j += 16) {
        unsigned o0 = ((unsigned)csr[j + lg] << 7) | boff;
        unsigned o1 = ((unsigned)csr[j + 4 + lg] << 7) | boff;
        unsigned o2 = ((unsigned)csr[j + 8 + lg] << 7) | boff;
        unsigned o3 = ((unsigned)csr[j + 12 + lg] << 7) | boff;
        uint2 r0 = *(const uint2*)&T[o0];
        uint2 r1 = *(const uint2*)&T[o1];
        uint2 r2 = *(const uint2*)&T[o2];
        uint2 r3 = *(const uint2*)&T[o3];
        a0 += uflo(r0.x); a1 += ufhi(r0.x); a2 += uflo(r0.y); a3 += ufhi(r0.y);
        a0 += uflo(r1.x); a1 += ufhi(r1.x); a2 += uflo(r1.y); a3 += ufhi(r1.y);
        a0 += uflo(r2.x); a1 += ufhi(r2.x); a2 += uflo(r2.y); a3 += ufhi(r2.y);
        a0 += uflo(r3.x); a1 += ufhi(r3.x); a2 += uflo(r3.y); a3 += ufhi(r3.y);
    }
    if (j < e) {
#pragma unroll
        for (int t = 0; t < 4; ++t) {
            int pos = j + 4 * t + lg;
            int ok = pos < e;
            unsigned oo = ((unsigned)csr[ok ? pos : s] << 7) | boff;
            uint2 r = *(const uint2*)&T[oo];
            float m = ok ? 1.f : 0.f;
            a0 += m * uflo(r.x); a1 += m * ufhi(r.x);
            a2 += m * uflo(r.y); a3 += m * ufhi(r.y);
        }
    }
    a0 += __shfl_xor(a0, 16, 64);  a1 += __shfl_xor(a1, 16, 64);
    a2 += __shfl_xor(a2, 16, 64);  a3 += __shfl_xor(a3, 16, 64);
    a0 += __shfl_xor(a0, 32, 64);  a1 += __shfl_xor(a1, 32, 64);
    a2 += __shfl_xor(a2, 32, 64);  a3 += __shfl_xor(a3, 32, 64);
    if (lg == 0) {
        float inv = 1.0f / fmaxf((float)(e - s), 1.0f);
        uint2 o;
        o.x = (unsigned)f2bf(a0 * inv) | ((unsigned)f2bf(a1 * inv) << 16);
        o.y = (unsigned)f2bf(a2 * inv) | ((unsigned)f2bf(a3 * inv) << 16);
        *(uint2*)&Out[((unsigned)n << 7) | ((unsigned)fq * 4u)] = o;
    }
}

// ---------------- fused MFMA GEMM: ab/cd = wv . relu(layer1(xa)) ----------------
// W1' pre-converted bf16 + pre-swizzled -> stage = straight uint4 memcpy.
// 512 thr = 8 waves x 16 nodes = 128 nodes/block. h1 in per-wave LDS tile.
__global__ __launch_bounds__(512) void fused_gemm_kernel(
        const unsigned short* __restrict__ A,
        const unsigned short* __restrict__ w1bf, const float* __restrict__ b1,
        const float* __restrict__ wv,
        float* __restrict__ ab, float* __restrict__ cd, long N) {
    __shared__ __align__(16) unsigned short wbuf[128 * 128];
    __shared__ __align__(16) unsigned short h1t[8][16 * 128];
    __shared__ float bs1[128];
    __shared__ float wvs[512];
    int tid = threadIdx.x;

    {
        const uint4* src = (const uint4*)w1bf;
        uint4* dst = (uint4*)wbuf;
#pragma unroll
        for (int i = 0; i < 4; ++i) dst[tid + i * 512] = src[tid + i * 512];
    }
    if (tid < 128) bs1[tid] = b1[tid];
    wvs[tid] = wv[tid];
    __syncthreads();

    int lane = tid & 63, wid = tid >> 6;
    int l16 = lane & 15, lg = lane >> 4;
    long n0 = (long)blockIdx.x * 128 + wid * 16;
    const unsigned short* A0 = A + (n0 + l16) * 128;
    unsigned short* hw = h1t[wid];

    f32x4 acc[8];
#pragma unroll
    for (int ot = 0; ot < 8; ++ot) acc[ot] = (f32x4){0.f, 0.f, 0.f, 0.f};

    // ---- phase 1: h1 = relu(xa @ W1'.T + b1) ----
#pragma unroll
    for (int ks = 0; ks < 4; ++ks) {
        int k0 = ks * 32;
        bf16x8 a = *(const bf16x8*)&A0[k0 + 8 * lg];
#pragma unroll
        for (int ot = 0; ot < 8; ++ot) {
            int o = ot * 16 + l16;
            bf16x8 b = *(const bf16x8*)&wbuf[(o * 128 + k0 + 8 * lg) ^ ((o & 7) << 3)];
            acc[ot] = __builtin_amdgcn_mfma_f32_16x16x32_bf16(a, b, acc[ot], 0, 0, 0);
        }
    }
    // epilogue 1 -> own-wave LDS tile (row = node-local, col = o), swizzled
#pragma unroll
    for (int j = 0; j < 4; ++j) {
        int row = lg * 4 + j;
#pragma unroll
        for (int ot = 0; ot < 8; ++ot) {
            int col = ot * 16 + l16;
            float v = fmaxf(acc[ot][j] + bs1[col], 0.f);
            hw[(row * 128 + col) ^ ((row & 7) << 3)] = f2bf(v);
        }
    }
    __syncthreads();

    // ---- phase 2: per-node scalars da,db,dc,dd = h1 . wv[0..3] (fp32) ----
    float da = 0.f, db = 0.f, dc = 0.f, dd = 0.f;
    int nl = l16;
#pragma unroll
    for (int t = 0; t < 4; ++t) {
        bf16x8 h = *(const bf16x8*)&hw[(nl * 128 + lg * 32 + t * 8) ^ ((nl & 7) << 3)];
#pragma unroll
        for (int e2 = 0; e2 < 8; ++e2) {
            float hv = b2f((unsigned short)h[e2]);
            int k = lg * 32 + t * 8 + e2;
            da += hv * wvs[k];       db += hv * wvs[128 + k];
            dc += hv * wvs[256 + k]; dd += hv * wvs[384 + k];
        }
    }
    da += __shfl_xor(da, 16, 64); db += __shfl_xor(db, 16, 64);
    dc += __shfl_xor(dc, 16, 64); dd += __shfl_xor(dd, 16, 64);
    da += __shfl_xor(da, 32, 64); db += __shfl_xor(db, 32, 64);
    dc += __shfl_xor(dc, 32, 64); dd += __shfl_xor(dd, 32, 64);
    long n = n0 + nl;
    if (lg == 0 && n < N) {
        *(float2*)&ab[n * 2] = make_float2(da, db);
        *(float2*)&cd[n * 2] = make_float2(dc, dd);
    }
}

// ---------------- scalar gather: UV[n] = (mean_nbr a + c[n], mean_nbr b + d[n]) ----------------
__global__ void sgather_kernel(const int* __restrict__ rs, const int* __restrict__ csr,
                               const float* __restrict__ ab, const float* __restrict__ cd,
                               float* __restrict__ UV, long N) {
    long n = (long)blockIdx.x * 256 + threadIdx.x;
    if (n >= N) return;
    int s = rs[n], e = rs[n + 1];
    float sa = 0.f, sb = 0.f;
    int j = s;
    for (; j + 4 <= e; j += 4) {
        unsigned i0 = (unsigned)csr[j] * 2u, i1 = (unsigned)csr[j + 1] * 2u;
        unsigned i2 = (unsigned)csr[j + 2] * 2u, i3 = (unsigned)csr[j + 3] * 2u;
        float2 v0 = *(const float2*)&ab[i0];
        float2 v1 = *(const float2*)&ab[i1];
        float2 v2 = *(const float2*)&ab[i2];
        float2 v3 = *(const float2*)&ab[i3];
        sa += (v0.x + v1.x) + (v2.x + v3.x);
        sb += (v0.y + v1.y) + (v2.y + v3.y);
    }
    for (; j < e; ++j) {
        float2 v = *(const float2*)&ab[(unsigned)csr[j] * 2u];
        sa += v.x; sb += v.y;
    }
    float inv = 1.0f / fmaxf((float)(e - s), 1.0f);
    float2 cdv = *(const float2*)&cd[n * 2];
    *(float2*)&UV[n * 2] = make_float2(sa * inv + cdv.x, sb * inv + cdv.y);
}

// linkpred: out[p] = sigmoid(U[s] + V[d] + C)
__global__ void linkpred_kernel(const void* pairs, const int* flag,
                                const float* __restrict__ UV, const float* __restrict__ wv,
                                float* __restrict__ out, long P) {
    long p = (long)blockIdx.x * 256 + threadIdx.x;
    if (p >= P) return;
    int is64 = *flag;
    long s = load_idx(pairs, 2 * p, is64);
    long d = load_idx(pairs, 2 * p + 1, is64);
    float acc = UV[s * 2] + UV[d * 2 + 1] + wv[512];
    out[p] = 1.0f / (1.0f + expf(-acc));
}

extern "C" void kernel_launch(void* const* d_in, const int* in_sizes, int n_in,
                              void* d_out, int out_size, void* d_ws, size_t ws_size,
                              hipStream_t stream) {
    const float* x    = (const float*)d_in[0];
    const void*  eidx  = d_in[1];
    const void*  pairs = d_in[2];
    const float* W1l = (const float*)d_in[3];
    const float* W1r = (const float*)d_in[4];
    const float* b1  = (const float*)d_in[5];
    const float* W2l = (const float*)d_in[6];
    const float* W2r = (const float*)d_in[7];
    const float* b2  = (const float*)d_in[8];
    const float* Wlp = (const float*)d_in[9];
    const float* blp = (const float*)d_in[10];
    float* out = (float*)d_out;

    long N = in_sizes[0] / 64;
    long E = in_sizes[1] / 2;
    long P = in_sizes[2] / 2;
    long NP = (N + 127) & ~127L;
    int NBK = (int)((N + 255) >> 8);          // <= 512
    int chunk = (int)((E + NBLK_A - 1) / NBLK_A);
    int xcb = (int)((N * 16 + 255) / 256);

    char* w = (char*)d_ws;
    auto alloc = [&](size_t bytes) {
        char* p = w;
        w += (bytes + 255) & ~(size_t)255;
        return p;
    };
    int* row_start = (int*)alloc((N + 1) * sizeof(int));
    int* csr_src   = (int*)alloc(E * sizeof(int));
    int* blk_hist  = (int*)alloc((size_t)NBK * NBLK_A * sizeof(int));
    int* total     = (int*)alloc(NBK * sizeof(int));
    int* base      = (int*)alloc((NBK + 1) * sizeof(int));
    int* flag      = (int*)alloc(64);
    unsigned* ebuf = (unsigned*)alloc(E * sizeof(unsigned));
    unsigned short* xa   = (unsigned short*)alloc((size_t)NP * 128 * 2);
    unsigned short* w1bf = (unsigned short*)alloc(16384 * 2);
    float* ab = (float*)alloc((size_t)N * 2 * sizeof(float));
    float* cd = (float*)alloc((size_t)N * 2 * sizeof(float));
    float* UV = (float*)alloc((size_t)N * 2 * sizeof(float));
    float* wv = (float*)alloc(1024 * sizeof(float));

    unsigned pre_blocks = (unsigned)(NBLK_A + xcb + 1);
    pre_kernel<<<pre_blocks, 256, 0, stream>>>(eidx, x, W1l, W1r, W2l, W2r, b2, Wlp, blp,
                                               blk_hist, xa, w1bf, wv, flag,
                                               N, E, NBK, chunk, xcb);

    bucket_total_kernel<<<NBK, 256, 0, stream>>>(blk_hist, total);
    bucket_base_kernel<<<1, 1, 0, stream>>>(total, base, row_start, NBK, N, E);
    bucket_off_kernel<<<NBK, 256, 0, stream>>>(blk_hist, base);
    bucket_scatter_kernel<<<NBLK_A, 256, 0, stream>>>(eidx, flag, blk_hist, ebuf, E, NBK, chunk);
    bucket_csr_kernel<<<NBK, 256, 0, stream>>>(ebuf, base, csr_src, row_start, N);

    unsigned gth_blocks = (unsigned)((N * 64 + 255) / 256);
    gather_kernel<<<gth_blocks, 256, 0, stream>>>(row_start, csr_src, xa, xa, N);

    unsigned gblocks = (unsigned)(NP / 128);
    fused_gemm_kernel<<<gblocks, 512, 0, stream>>>(xa, w1bf, b1, wv, ab, cd, N);

    unsigned sgblocks = (unsigned)((N + 255) / 256);
    sgather_kernel<<<sgblocks, 256, 0, stream>>>(row_start, csr_src, ab, cd, UV, N);

    unsigned pblocks = (unsigned)((P + 255) / 256);
    linkpred_kernel<<<pblocks, 256, 0, stream>>>(pairs, flag, UV, wv, out, P);
}

// Round 12
// 148.301 us; speedup vs baseline: 1.8478x; 1.0214x over previous
//
#include <hip/hip_runtime.h>

// GraphSAGE 2-layer + link predictor, layer-2 collapsed to 4 scalars/node.
// pre(count || xcast || {flag,wv,W1'bf16}) -> relscan(+total) -> base -> scatter -> csr
// -> fused_gg (gather agg into LDS + MFMA layer1 + in-register collapse) -> sgather -> linkpred.

typedef __attribute__((ext_vector_type(8))) short bf16x8;
typedef __attribute__((ext_vector_type(4))) float f32x4;

#define NBLK_A 256   // blocks in edge-chunk passes

__device__ __forceinline__ unsigned short f2bf(float f) {
    unsigned u = __float_as_uint(f);
    u = u + 0x7fffu + ((u >> 16) & 1u);   // RTNE
    return (unsigned short)(u >> 16);
}
__device__ __forceinline__ float b2f(unsigned short s) {
    return __uint_as_float(((unsigned)s) << 16);
}
__device__ __forceinline__ float uflo(unsigned v) { return __uint_as_float(v << 16); }
__device__ __forceinline__ float ufhi(unsigned v) { return __uint_as_float(v & 0xffff0000u); }

__device__ __forceinline__ long load_idx(const void* p, long i, int is64) {
    if (is64) return (long)((const long long*)p)[i];
    return (long)((const int*)p)[i];
}

__device__ __forceinline__ int detect64_local(const void* p) {
    const unsigned* u = (const unsigned*)p;
    unsigned a = 0;
#pragma unroll
    for (int i = 0; i < 32; ++i) a |= u[2 * i + 1];
    return a == 0u;
}

// ---------------- pre: bucket_count || xcast || prep ----------------
__global__ void pre_kernel(const void* eidx, const float* __restrict__ x,
                           const float* __restrict__ W1l, const float* __restrict__ W1r,
                           const float* __restrict__ W2l, const float* __restrict__ W2r,
                           const float* __restrict__ b2, const float* __restrict__ Wlp,
                           const float* __restrict__ blp,
                           int* __restrict__ blk_hist, unsigned short* __restrict__ xaown,
                           unsigned short* __restrict__ w1bf, float* __restrict__ wv,
                           int* __restrict__ flag,
                           long N, long E, int NBK, int chunk, int xcb) {
    int b = blockIdx.x;
    int tid = threadIdx.x;
    if (b < NBLK_A) {
        __shared__ int h[512];
        for (int i = tid; i < NBK; i += 256) h[i] = 0;
        __syncthreads();
        int is64 = detect64_local(eidx);
        long e0 = (long)b * chunk;
        long e1 = e0 + chunk; if (e1 > E) e1 = E;
        for (long e = e0 + tid; e < e1; e += 256) {
            long dst = load_idx(eidx, E + e, is64);
            atomicAdd(&h[(int)(dst >> 8)], 1);
        }
        __syncthreads();
        for (int i = tid; i < NBK; i += 256) blk_hist[i * NBLK_A + b] = h[i];
    } else if (b < NBLK_A + xcb) {
        long t = (long)(b - NBLK_A) * 256 + tid;
        long n = t >> 4;
        int q = (int)(t & 15);
        if (n >= N) return;
        float4 v = *(const float4*)&x[n * 64 + q * 4];
        uint2 u;
        u.x = (unsigned)f2bf(v.x) | ((unsigned)f2bf(v.y) << 16);
        u.y = (unsigned)f2bf(v.z) | ((unsigned)f2bf(v.w) << 16);
        *(uint2*)&xaown[n * 64 + q * 4] = u;
    } else {
        if (tid == 0) *flag = detect64_local(eidx);
        if (tid < 128) {
            int k = tid;
            float s0 = 0.f, s1 = 0.f, s2 = 0.f, s3 = 0.f;
            for (int o = 0; o < 64; ++o) {
                float wl = Wlp[o], wr = Wlp[64 + o];
                float l = W2l[o * 128 + k], r = W2r[o * 128 + k];
                s0 += wl * l; s1 += wr * l; s2 += wl * r; s3 += wr * r;
            }
            wv[k] = s0; wv[128 + k] = s1; wv[256 + k] = s2; wv[384 + k] = s3;
            if (k == 0) {
                float c = blp[0];
                for (int o = 0; o < 64; ++o) c += (Wlp[o] + Wlp[64 + o]) * b2[o];
                wv[512] = c;
            }
        }
        // W1' bf16, PRE-SWIZZLED: element (o*128+k) stored at index ^ ((o&7)<<3)
        for (int i = tid; i < 16384; i += 256) {
            int o = i >> 7, k = i & 127;
            float f = (k < 64) ? W1l[o * 64 + k] : W1r[o * 64 + (k - 64)];
            w1bf[i ^ ((o & 7) << 3)] = f2bf(f);
        }
    }
}

// relscan: blk_hist row -> exclusive within-row scan (no base); total[k] = row sum.
__global__ void bucket_relscan_kernel(int* __restrict__ blk_hist, int* __restrict__ total) {
    __shared__ int ts[256];
    int k = blockIdx.x, t = threadIdx.x;
    int v = blk_hist[k * NBLK_A + t];
    ts[t] = v; __syncthreads();
    for (int off = 1; off < 256; off <<= 1) {
        int u = (t >= off) ? ts[t - off] : 0;
        __syncthreads();
        ts[t] += u;
        __syncthreads();
    }
    blk_hist[k * NBLK_A + t] = ts[t] - v;
    if (t == 255) total[k] = ts[255];
}

// base: parallel exclusive scan over up to 512 bucket totals.
__global__ void base_kernel(const int* __restrict__ total, int* __restrict__ base,
                            int* __restrict__ row_start, int NBK, long N, long E) {
    __shared__ int ts[256];
    int t = threadIdx.x;
    int a = (t < NBK) ? total[t] : 0;
    int b = (256 + t < NBK) ? total[256 + t] : 0;
    ts[t] = a; __syncthreads();
    for (int off = 1; off < 256; off <<= 1) {
        int u = (t >= off) ? ts[t - off] : 0;
        __syncthreads();
        ts[t] += u;
        __syncthreads();
    }
    int incl1 = ts[t];
    int sum1 = ts[255];
    if (t < NBK) base[t] = incl1 - a;
    __syncthreads();
    ts[t] = b; __syncthreads();
    for (int off = 1; off < 256; off <<= 1) {
        int u = (t >= off) ? ts[t - off] : 0;
        __syncthreads();
        ts[t] += u;
        __syncthreads();
    }
    int incl2 = ts[t];
    if (256 + t < NBK) base[256 + t] = sum1 + incl2 - b;
    if (t == 255) base[NBK] = sum1 + incl2;
    if (t == 0) row_start[N] = (int)E;
}

// scatter: cursor = relative offset + base[k].
__global__ void bucket_scatter_kernel(const void* eidx, const int* flag,
                                      const int* __restrict__ blk_hist, const int* __restrict__ base,
                                      unsigned* __restrict__ ebuf, long E, int NBK, int chunk) {
    __shared__ int cur[512];
    int tid = threadIdx.x, b = blockIdx.x;
    for (int i = tid; i < NBK; i += 256) cur[i] = blk_hist[i * NBLK_A + b] + base[i];
    __syncthreads();
    int is64 = *flag;
    long e0 = (long)b * chunk;
    long e1 = e0 + chunk; if (e1 > E) e1 = E;
    for (long e = e0 + tid; e < e1; e += 256) {
        long src = load_idx(eidx, e, is64);
        long dst = load_idx(eidx, E + e, is64);
        int pos = atomicAdd(&cur[(int)(dst >> 8)], 1);
        ebuf[pos] = (unsigned)src | ((unsigned)(dst & 255) << 24);  // src < 2^24
    }
}

// per-bucket counting sort in LDS -> coalesced row_start + L2-local csr writes.
__global__ void bucket_csr_kernel(const unsigned* __restrict__ ebuf, const int* __restrict__ base,
                                  int* __restrict__ csr_src, int* __restrict__ row_start, long N) {
    __shared__ int cnt[256], sc[256], cur[256];
    int k = blockIdx.x, t = threadIdx.x;
    int bstart = base[k], bend = base[k + 1];
    cnt[t] = 0;
    __syncthreads();
    for (int i = bstart + t; i < bend; i += 256)
        atomicAdd(&cnt[ebuf[i] >> 24], 1);
    __syncthreads();
    int c = cnt[t];
    sc[t] = c; __syncthreads();
    for (int off = 1; off < 256; off <<= 1) {
        int u = (t >= off) ? sc[t - off] : 0;
        __syncthreads();
        sc[t] += u;
        __syncthreads();
    }
    int loff = sc[t] - c;
    cur[t] = loff;
    long n = (long)k * 256 + t;
    if (n < N) row_start[n] = bstart + loff;
    __syncthreads();
    for (int i = bstart + t; i < bend; i += 256) {
        unsigned v = ebuf[i];
        int dl = (int)(v >> 24);
        int p = atomicAdd(&cur[dl], 1);
        csr_src[bstart + p] = (int)(v & 0xFFFFFFu);
    }
}

// ---------------- fused gather + GEMM + collapse ----------------
// 512 thr = 8 waves x 16 nodes = 128 nodes/block.
// Per wave: gather its 16 nodes' neighbor means (v3 pattern, 16 lines in flight)
// into a swizzled LDS tile; MFMA ks0-1 from LDS agg, ks2-3 from global own-half;
// phase 2 = in-register relu+bias+4 dots, shfl-reduced over 16 lanes.
__global__ __launch_bounds__(512, 4) void fused_gg_kernel(
        const int* __restrict__ rs, const int* __restrict__ csr,
        const unsigned short* __restrict__ xaown,   // [n][64] bf16
        const unsigned short* __restrict__ w1bf, const float* __restrict__ b1,
        const float* __restrict__ wv,
        float* __restrict__ ab, float* __restrict__ cd, long N) {
    __shared__ __align__(16) unsigned short wbuf[128 * 128];  // 32 KB
    __shared__ __align__(16) unsigned short aggt[8][16 * 64]; // 16 KB
    __shared__ float bs1[128];
    __shared__ float wvs[512];
    int tid = threadIdx.x;

    {   // stage pre-swizzled W1' (straight memcpy)
        const uint4* src = (const uint4*)w1bf;
        uint4* dst = (uint4*)wbuf;
#pragma unroll
        for (int i = 0; i < 4; ++i) dst[tid + i * 512] = src[tid + i * 512];
    }
    if (tid < 128) bs1[tid] = b1[tid];
    wvs[tid] = wv[tid];

    int lane = tid & 63, wid = tid >> 6;
    int l16 = lane & 15, lg = lane >> 4;
    long n0 = (long)blockIdx.x * 128 + wid * 16;
    unsigned short* agg = aggt[wid];
    unsigned boff = (unsigned)l16 * 4u;

    // ---- gather phase: 16 nodes per wave ----
    for (int nl = 0; nl < 16; ++nl) {
        long n = n0 + nl;
        int s = 0, e = 0;
        if (n < N) { s = rs[n]; e = rs[n + 1]; }
        float a0 = 0.f, a1 = 0.f, a2 = 0.f, a3 = 0.f;
        int j = s;
        for (; j + 16 <= e; j += 16) {
            unsigned o0 = ((unsigned)csr[j + lg] << 6) | boff;
            unsigned o1 = ((unsigned)csr[j + 4 + lg] << 6) | boff;
            unsigned o2 = ((unsigned)csr[j + 8 + lg] << 6) | boff;
            unsigned o3 = ((unsigned)csr[j + 12 + lg] << 6) | boff;
            uint2 r0 = *(const uint2*)&xaown[o0];
            uint2 r1 = *(const uint2*)&xaown[o1];
            uint2 r2 = *(const uint2*)&xaown[o2];
            uint2 r3 = *(const uint2*)&xaown[o3];
            a0 += uflo(r0.x); a1 += ufhi(r0.x); a2 += uflo(r0.y); a3 += ufhi(r0.y);
            a0 += uflo(r1.x); a1 += ufhi(r1.x); a2 += uflo(r1.y); a3 += ufhi(r1.y);
            a0 += uflo(r2.x); a1 += ufhi(r2.x); a2 += uflo(r2.y); a3 += ufhi(r2.y);
            a0 += uflo(r3.x); a1 += ufhi(r3.x); a2 += uflo(r3.y); a3 += ufhi(r3.y);
        }
        if (j < e) {
#pragma unroll
            for (int t = 0; t < 4; ++t) {
                int pos = j + 4 * t + lg;
                int ok = pos < e;
                unsigned oo = ((unsigned)csr[ok ? pos : s] << 6) | boff;
                uint2 r = *(const uint2*)&xaown[oo];
                float m = ok ? 1.f : 0.f;
                a0 += m * uflo(r.x); a1 += m * ufhi(r.x);
                a2 += m * uflo(r.y); a3 += m * ufhi(r.y);
            }
        }
        a0 += __shfl_xor(a0, 16, 64);  a1 += __shfl_xor(a1, 16, 64);
        a2 += __shfl_xor(a2, 16, 64);  a3 += __shfl_xor(a3, 16, 64);
        a0 += __shfl_xor(a0, 32, 64);  a1 += __shfl_xor(a1, 32, 64);
        a2 += __shfl_xor(a2, 32, 64);  a3 += __shfl_xor(a3, 32, 64);
        if (lg == 0) {
            float inv = 1.0f / fmaxf((float)(e - s), 1.0f);
            uint2 o;
            o.x = (unsigned)f2bf(a0 * inv) | ((unsigned)f2bf(a1 * inv) << 16);
            o.y = (unsigned)f2bf(a2 * inv) | ((unsigned)f2bf(a3 * inv) << 16);
            int eo = (l16 * 4) ^ ((nl & 7) << 3);
            *(uint2*)&agg[nl * 64 + eo] = o;
        }
    }
    __syncthreads();   // wbuf/bs1/wvs staging + (wave-local agg ordered anyway)

    // ---- MFMA: h1 = relu(A' @ W1'.T + b1), A' = [agg | own] ----
    f32x4 acc[8];
#pragma unroll
    for (int ot = 0; ot < 8; ++ot) acc[ot] = (f32x4){0.f, 0.f, 0.f, 0.f};
    const unsigned short* A0 = xaown + (n0 + l16) * 64;
#pragma unroll
    for (int ks = 0; ks < 4; ++ks) {
        int k0 = ks * 32;
        bf16x8 a;
        if (ks < 2) a = *(const bf16x8*)&agg[l16 * 64 + ((k0 + 8 * lg) ^ ((l16 & 7) << 3))];
        else        a = *(const bf16x8*)&A0[(k0 - 64) + 8 * lg];
#pragma unroll
        for (int ot = 0; ot < 8; ++ot) {
            int o = ot * 16 + l16;
            bf16x8 b = *(const bf16x8*)&wbuf[(o * 128 + k0 + 8 * lg) ^ ((o & 7) << 3)];
            acc[ot] = __builtin_amdgcn_mfma_f32_16x16x32_bf16(a, b, acc[ot], 0, 0, 0);
        }
    }

    // ---- phase 2 in registers: per row (node) da..dd = relu(h1).wv[0..3] ----
#pragma unroll
    for (int j = 0; j < 4; ++j) {
        float da = 0.f, db = 0.f, dc = 0.f, dd = 0.f;
#pragma unroll
        for (int ot = 0; ot < 8; ++ot) {
            int col = ot * 16 + l16;
            float hv = fmaxf(acc[ot][j] + bs1[col], 0.f);
            da += hv * wvs[col];       db += hv * wvs[128 + col];
            dc += hv * wvs[256 + col]; dd += hv * wvs[384 + col];
        }
        // reduce across the 16 l16 lanes (lane bits 0..3)
        da += __shfl_xor(da, 1, 64); db += __shfl_xor(db, 1, 64);
        dc += __shfl_xor(dc, 1, 64); dd += __shfl_xor(dd, 1, 64);
        da += __shfl_xor(da, 2, 64); db += __shfl_xor(db, 2, 64);
        dc += __shfl_xor(dc, 2, 64); dd += __shfl_xor(dd, 2, 64);
        da += __shfl_xor(da, 4, 64); db += __shfl_xor(db, 4, 64);
        dc += __shfl_xor(dc, 4, 64); dd += __shfl_xor(dd, 4, 64);
        da += __shfl_xor(da, 8, 64); db += __shfl_xor(db, 8, 64);
        dc += __shfl_xor(dc, 8, 64); dd += __shfl_xor(dd, 8, 64);
        long n = n0 + lg * 4 + j;
        if (l16 == 0 && n < N) {
            *(float2*)&ab[n * 2] = make_float2(da, db);
            *(float2*)&cd[n * 2] = make_float2(dc, dd);
        }
    }
}

// ---------------- scalar gather: UV[n] = (mean_nbr a + c[n], mean_nbr b + d[n]) ----------------
__global__ void sgather_kernel(const int* __restrict__ rs, const int* __restrict__ csr,
                               const float* __restrict__ ab, const float* __restrict__ cd,
                               float* __restrict__ UV, long N) {
    long n = (long)blockIdx.x * 256 + threadIdx.x;
    if (n >= N) return;
    int s = rs[n], e = rs[n + 1];
    float sa = 0.f, sb = 0.f;
    int j = s;
    for (; j + 4 <= e; j += 4) {
        unsigned i0 = (unsigned)csr[j] * 2u, i1 = (unsigned)csr[j + 1] * 2u;
        unsigned i2 = (unsigned)csr[j + 2] * 2u, i3 = (unsigned)csr[j + 3] * 2u;
        float2 v0 = *(const float2*)&ab[i0];
        float2 v1 = *(const float2*)&ab[i1];
        float2 v2 = *(const float2*)&ab[i2];
        float2 v3 = *(const float2*)&ab[i3];
        sa += (v0.x + v1.x) + (v2.x + v3.x);
        sb += (v0.y + v1.y) + (v2.y + v3.y);
    }
    for (; j < e; ++j) {
        float2 v = *(const float2*)&ab[(unsigned)csr[j] * 2u];
        sa += v.x; sb += v.y;
    }
    float inv = 1.0f / fmaxf((float)(e - s), 1.0f);
    float2 cdv = *(const float2*)&cd[n * 2];
    *(float2*)&UV[n * 2] = make_float2(sa * inv + cdv.x, sb * inv + cdv.y);
}

// linkpred: out[p] = sigmoid(U[s] + V[d] + C)
__global__ void linkpred_kernel(const void* pairs, const int* flag,
                                const float* __restrict__ UV, const float* __restrict__ wv,
                                float* __restrict__ out, long P) {
    long p = (long)blockIdx.x * 256 + threadIdx.x;
    if (p >= P) return;
    int is64 = *flag;
    long s = load_idx(pairs, 2 * p, is64);
    long d = load_idx(pairs, 2 * p + 1, is64);
    float acc = UV[s * 2] + UV[d * 2 + 1] + wv[512];
    out[p] = 1.0f / (1.0f + expf(-acc));
}

extern "C" void kernel_launch(void* const* d_in, const int* in_sizes, int n_in,
                              void* d_out, int out_size, void* d_ws, size_t ws_size,
                              hipStream_t stream) {
    const float* x    = (const float*)d_in[0];
    const void*  eidx  = d_in[1];
    const void*  pairs = d_in[2];
    const float* W1l = (const float*)d_in[3];
    const float* W1r = (const float*)d_in[4];
    const float* b1  = (const float*)d_in[5];
    const float* W2l = (const float*)d_in[6];
    const float* W2r = (const float*)d_in[7];
    const float* b2  = (const float*)d_in[8];
    const float* Wlp = (const float*)d_in[9];
    const float* blp = (const float*)d_in[10];
    float* out = (float*)d_out;

    long N = in_sizes[0] / 64;
    long E = in_sizes[1] / 2;
    long P = in_sizes[2] / 2;
    long NP = (N + 127) & ~127L;
    int NBK = (int)((N + 255) >> 8);          // <= 512
    int chunk = (int)((E + NBLK_A - 1) / NBLK_A);
    int xcb = (int)((N * 16 + 255) / 256);

    char* w = (char*)d_ws;
    auto alloc = [&](size_t bytes) {
        char* p = w;
        w += (bytes + 255) & ~(size_t)255;
        return p;
    };
    int* row_start = (int*)alloc((N + 1) * sizeof(int));
    int* csr_src   = (int*)alloc(E * sizeof(int));
    int* blk_hist  = (int*)alloc((size_t)NBK * NBLK_A * sizeof(int));
    int* total     = (int*)alloc(NBK * sizeof(int));
    int* base      = (int*)alloc((NBK + 1) * sizeof(int));
    int* flag      = (int*)alloc(64);
    unsigned* ebuf = (unsigned*)alloc(E * sizeof(unsigned));
    unsigned short* xaown = (unsigned short*)alloc((size_t)NP * 64 * 2);
    unsigned short* w1bf  = (unsigned short*)alloc(16384 * 2);
    float* ab = (float*)alloc((size_t)N * 2 * sizeof(float));
    float* cd = (float*)alloc((size_t)N * 2 * sizeof(float));
    float* UV = (float*)alloc((size_t)N * 2 * sizeof(float));
    float* wv = (float*)alloc(1024 * sizeof(float));

    unsigned pre_blocks = (unsigned)(NBLK_A + xcb + 1);
    pre_kernel<<<pre_blocks, 256, 0, stream>>>(eidx, x, W1l, W1r, W2l, W2r, b2, Wlp, blp,
                                               blk_hist, xaown, w1bf, wv, flag,
                                               N, E, NBK, chunk, xcb);

    bucket_relscan_kernel<<<NBK, 256, 0, stream>>>(blk_hist, total);
    base_kernel<<<1, 256, 0, stream>>>(total, base, row_start, NBK, N, E);
    bucket_scatter_kernel<<<NBLK_A, 256, 0, stream>>>(eidx, flag, blk_hist, base, ebuf, E, NBK, chunk);
    bucket_csr_kernel<<<NBK, 256, 0, stream>>>(ebuf, base, csr_src, row_start, N);

    unsigned gblocks = (unsigned)(NP / 128);
    fused_gg_kernel<<<gblocks, 512, 0, stream>>>(row_start, csr_src, xaown, w1bf, b1, wv, ab, cd, N);

    unsigned sgblocks = (unsigned)((N + 255) / 256);
    sgather_kernel<<<sgblocks, 256, 0, stream>>>(row_start, csr_src, ab, cd, UV, N);

    unsigned pblocks = (unsigned)((P + 255) / 256);
    linkpred_kernel<<<pblocks, 256, 0, stream>>>(pairs, flag, UV, wv, out, P);
}

// Round 13
// 131.377 us; speedup vs baseline: 2.0858x; 1.1288x over previous
//
#include <hip/hip_runtime.h>

// GraphSAGE 2-layer + link predictor, layer-2 collapsed to 4 scalars/node.
// pre(count || xcast || {flag,wv,W1'bf16}) -> relscan(+total) -> base -> scatter -> csr
// -> gather (xagg, 1 wave/node) -> fused_gemm (A from global, in-register collapse)
// -> sgather -> linkpred.

typedef __attribute__((ext_vector_type(8))) short bf16x8;
typedef __attribute__((ext_vector_type(4))) float f32x4;

#define NBLK_A 256   // blocks in edge-chunk passes

__device__ __forceinline__ unsigned short f2bf(float f) {
    unsigned u = __float_as_uint(f);
    u = u + 0x7fffu + ((u >> 16) & 1u);   // RTNE
    return (unsigned short)(u >> 16);
}
__device__ __forceinline__ float b2f(unsigned short s) {
    return __uint_as_float(((unsigned)s) << 16);
}
__device__ __forceinline__ float uflo(unsigned v) { return __uint_as_float(v << 16); }
__device__ __forceinline__ float ufhi(unsigned v) { return __uint_as_float(v & 0xffff0000u); }

__device__ __forceinline__ long load_idx(const void* p, long i, int is64) {
    if (is64) return (long)((const long long*)p)[i];
    return (long)((const int*)p)[i];
}

__device__ __forceinline__ int detect64_local(const void* p) {
    const unsigned* u = (const unsigned*)p;
    unsigned a = 0;
#pragma unroll
    for (int i = 0; i < 32; ++i) a |= u[2 * i + 1];
    return a == 0u;
}

// ---------------- pre: bucket_count || xcast || prep ----------------
__global__ void pre_kernel(const void* eidx, const float* __restrict__ x,
                           const float* __restrict__ W1l, const float* __restrict__ W1r,
                           const float* __restrict__ W2l, const float* __restrict__ W2r,
                           const float* __restrict__ b2, const float* __restrict__ Wlp,
                           const float* __restrict__ blp,
                           int* __restrict__ blk_hist, unsigned short* __restrict__ xaown,
                           unsigned short* __restrict__ w1bf, float* __restrict__ wv,
                           int* __restrict__ flag,
                           long N, long E, int NBK, int chunk, int xcb) {
    int b = blockIdx.x;
    int tid = threadIdx.x;
    if (b < NBLK_A) {
        __shared__ int h[512];
        for (int i = tid; i < NBK; i += 256) h[i] = 0;
        __syncthreads();
        int is64 = detect64_local(eidx);
        long e0 = (long)b * chunk;
        long e1 = e0 + chunk; if (e1 > E) e1 = E;
        for (long e = e0 + tid; e < e1; e += 256) {
            long dst = load_idx(eidx, E + e, is64);
            atomicAdd(&h[(int)(dst >> 8)], 1);
        }
        __syncthreads();
        for (int i = tid; i < NBK; i += 256) blk_hist[i * NBLK_A + b] = h[i];
    } else if (b < NBLK_A + xcb) {
        long t = (long)(b - NBLK_A) * 256 + tid;
        long n = t >> 4;
        int q = (int)(t & 15);
        if (n >= N) return;
        float4 v = *(const float4*)&x[n * 64 + q * 4];
        uint2 u;
        u.x = (unsigned)f2bf(v.x) | ((unsigned)f2bf(v.y) << 16);
        u.y = (unsigned)f2bf(v.z) | ((unsigned)f2bf(v.w) << 16);
        *(uint2*)&xaown[n * 64 + q * 4] = u;
    } else {
        if (tid == 0) *flag = detect64_local(eidx);
        if (tid < 128) {
            int k = tid;
            float s0 = 0.f, s1 = 0.f, s2 = 0.f, s3 = 0.f;
            for (int o = 0; o < 64; ++o) {
                float wl = Wlp[o], wr = Wlp[64 + o];
                float l = W2l[o * 128 + k], r = W2r[o * 128 + k];
                s0 += wl * l; s1 += wr * l; s2 += wl * r; s3 += wr * r;
            }
            wv[k] = s0; wv[128 + k] = s1; wv[256 + k] = s2; wv[384 + k] = s3;
            if (k == 0) {
                float c = blp[0];
                for (int o = 0; o < 64; ++o) c += (Wlp[o] + Wlp[64 + o]) * b2[o];
                wv[512] = c;
            }
        }
        // W1' bf16, PRE-SWIZZLED: element (o*128+k) stored at index ^ ((o&7)<<3)
        for (int i = tid; i < 16384; i += 256) {
            int o = i >> 7, k = i & 127;
            float f = (k < 64) ? W1l[o * 64 + k] : W1r[o * 64 + (k - 64)];
            w1bf[i ^ ((o & 7) << 3)] = f2bf(f);
        }
    }
}

// relscan: blk_hist row -> exclusive within-row scan (no base); total[k] = row sum.
__global__ void bucket_relscan_kernel(int* __restrict__ blk_hist, int* __restrict__ total) {
    __shared__ int ts[256];
    int k = blockIdx.x, t = threadIdx.x;
    int v = blk_hist[k * NBLK_A + t];
    ts[t] = v; __syncthreads();
    for (int off = 1; off < 256; off <<= 1) {
        int u = (t >= off) ? ts[t - off] : 0;
        __syncthreads();
        ts[t] += u;
        __syncthreads();
    }
    blk_hist[k * NBLK_A + t] = ts[t] - v;
    if (t == 255) total[k] = ts[255];
}

// base: parallel exclusive scan over up to 512 bucket totals.
__global__ void base_kernel(const int* __restrict__ total, int* __restrict__ base,
                            int* __restrict__ row_start, int NBK, long N, long E) {
    __shared__ int ts[256];
    int t = threadIdx.x;
    int a = (t < NBK) ? total[t] : 0;
    int b = (256 + t < NBK) ? total[256 + t] : 0;
    ts[t] = a; __syncthreads();
    for (int off = 1; off < 256; off <<= 1) {
        int u = (t >= off) ? ts[t - off] : 0;
        __syncthreads();
        ts[t] += u;
        __syncthreads();
    }
    int incl1 = ts[t];
    int sum1 = ts[255];
    if (t < NBK) base[t] = incl1 - a;
    __syncthreads();
    ts[t] = b; __syncthreads();
    for (int off = 1; off < 256; off <<= 1) {
        int u = (t >= off) ? ts[t - off] : 0;
        __syncthreads();
        ts[t] += u;
        __syncthreads();
    }
    int incl2 = ts[t];
    if (256 + t < NBK) base[256 + t] = sum1 + incl2 - b;
    if (t == 255) base[NBK] = sum1 + incl2;
    if (t == 0) row_start[N] = (int)E;
}

// scatter: cursor = relative offset + base[k].
__global__ void bucket_scatter_kernel(const void* eidx, const int* flag,
                                      const int* __restrict__ blk_hist, const int* __restrict__ base,
                                      unsigned* __restrict__ ebuf, long E, int NBK, int chunk) {
    __shared__ int cur[512];
    int tid = threadIdx.x, b = blockIdx.x;
    for (int i = tid; i < NBK; i += 256) cur[i] = blk_hist[i * NBLK_A + b] + base[i];
    __syncthreads();
    int is64 = *flag;
    long e0 = (long)b * chunk;
    long e1 = e0 + chunk; if (e1 > E) e1 = E;
    for (long e = e0 + tid; e < e1; e += 256) {
        long src = load_idx(eidx, e, is64);
        long dst = load_idx(eidx, E + e, is64);
        int pos = atomicAdd(&cur[(int)(dst >> 8)], 1);
        ebuf[pos] = (unsigned)src | ((unsigned)(dst & 255) << 24);  // src < 2^24
    }
}

// per-bucket counting sort in LDS -> coalesced row_start + L2-local csr writes.
__global__ void bucket_csr_kernel(const unsigned* __restrict__ ebuf, const int* __restrict__ base,
                                  int* __restrict__ csr_src, int* __restrict__ row_start, long N) {
    __shared__ int cnt[256], sc[256], cur[256];
    int k = blockIdx.x, t = threadIdx.x;
    int bstart = base[k], bend = base[k + 1];
    cnt[t] = 0;
    __syncthreads();
    for (int i = bstart + t; i < bend; i += 256)
        atomicAdd(&cnt[ebuf[i] >> 24], 1);
    __syncthreads();
    int c = cnt[t];
    sc[t] = c; __syncthreads();
    for (int off = 1; off < 256; off <<= 1) {
        int u = (t >= off) ? sc[t - off] : 0;
        __syncthreads();
        sc[t] += u;
        __syncthreads();
    }
    int loff = sc[t] - c;
    cur[t] = loff;
    long n = (long)k * 256 + t;
    if (n < N) row_start[n] = bstart + loff;
    __syncthreads();
    for (int i = bstart + t; i < bend; i += 256) {
        unsigned v = ebuf[i];
        int dl = (int)(v >> 24);
        int p = atomicAdd(&cur[dl], 1);
        csr_src[bstart + p] = (int)(v & 0xFFFFFFu);
    }
}

// ---------------- gather: xagg[n][64] = mean_nbr xaown[src][64] ----------------
// One wave per node (100K waves). Lane l: edge slot lg=l>>4, feature quad fq=l&15.
// 16 edges/iter: 4 idx loads + 4 row loads -> 16 lines in flight. 32-bit addressing.
__global__ void gather_kernel(const int* __restrict__ rs, const int* __restrict__ csr,
                              const unsigned short* __restrict__ T,
                              unsigned short* __restrict__ Out, long N) {
    long gid = (long)blockIdx.x * 256 + threadIdx.x;
    long n = gid >> 6;
    if (n >= N) return;
    int lane = (int)(gid & 63);
    int lg = lane >> 4;
    int fq = lane & 15;
    int s = rs[n], e = rs[n + 1];
    unsigned boff = (unsigned)fq * 4u;
    float a0 = 0.f, a1 = 0.f, a2 = 0.f, a3 = 0.f;
    int j = s;
    for (; j + 16 <= e; j += 16) {
        unsigned o0 = ((unsigned)csr[j + lg] << 6) | boff;
        unsigned o1 = ((unsigned)csr[j + 4 + lg] << 6) | boff;
        unsigned o2 = ((unsigned)csr[j + 8 + lg] << 6) | boff;
        unsigned o3 = ((unsigned)csr[j + 12 + lg] << 6) | boff;
        uint2 r0 = *(const uint2*)&T[o0];
        uint2 r1 = *(const uint2*)&T[o1];
        uint2 r2 = *(const uint2*)&T[o2];
        uint2 r3 = *(const uint2*)&T[o3];
        a0 += uflo(r0.x); a1 += ufhi(r0.x); a2 += uflo(r0.y); a3 += ufhi(r0.y);
        a0 += uflo(r1.x); a1 += ufhi(r1.x); a2 += uflo(r1.y); a3 += ufhi(r1.y);
        a0 += uflo(r2.x); a1 += ufhi(r2.x); a2 += uflo(r2.y); a3 += ufhi(r2.y);
        a0 += uflo(r3.x); a1 += ufhi(r3.x); a2 += uflo(r3.y); a3 += ufhi(r3.y);
    }
    if (j < e) {
#pragma unroll
        for (int t = 0; t < 4; ++t) {
            int pos = j + 4 * t + lg;
            int ok = pos < e;
            unsigned oo = ((unsigned)csr[ok ? pos : s] << 6) | boff;
            uint2 r = *(const uint2*)&T[oo];
            float m = ok ? 1.f : 0.f;
            a0 += m * uflo(r.x); a1 += m * ufhi(r.x);
            a2 += m * uflo(r.y); a3 += m * ufhi(r.y);
        }
    }
    a0 += __shfl_xor(a0, 16, 64);  a1 += __shfl_xor(a1, 16, 64);
    a2 += __shfl_xor(a2, 16, 64);  a3 += __shfl_xor(a3, 16, 64);
    a0 += __shfl_xor(a0, 32, 64);  a1 += __shfl_xor(a1, 32, 64);
    a2 += __shfl_xor(a2, 32, 64);  a3 += __shfl_xor(a3, 32, 64);
    if (lg == 0) {
        float inv = 1.0f / fmaxf((float)(e - s), 1.0f);
        uint2 o;
        o.x = (unsigned)f2bf(a0 * inv) | ((unsigned)f2bf(a1 * inv) << 16);
        o.y = (unsigned)f2bf(a2 * inv) | ((unsigned)f2bf(a3 * inv) << 16);
        *(uint2*)&Out[((unsigned)n << 6) | boff] = o;
    }
}

// ---------------- fused MFMA GEMM + collapse: ab/cd = wv . relu(layer1([agg|own])) ----------------
// A'[n][k]: k<64 -> xagg[n][k]; k>=64 -> xaown[n][k-64]. Direct global bf16x8 loads.
// 512 thr = 8 waves x 16 nodes = 128 nodes/block. LDS = wbuf 32K + 2.5K -> 4 blocks/CU.
__global__ __launch_bounds__(512) void fused_gemm_kernel(
        const unsigned short* __restrict__ xagg, const unsigned short* __restrict__ xaown,
        const unsigned short* __restrict__ w1bf, const float* __restrict__ b1,
        const float* __restrict__ wv,
        float* __restrict__ ab, float* __restrict__ cd, long N) {
    __shared__ __align__(16) unsigned short wbuf[128 * 128];
    __shared__ float bs1[128];
    __shared__ float wvs[512];
    int tid = threadIdx.x;

    {   // stage pre-swizzled W1' (straight memcpy)
        const uint4* src = (const uint4*)w1bf;
        uint4* dst = (uint4*)wbuf;
#pragma unroll
        for (int i = 0; i < 4; ++i) dst[tid + i * 512] = src[tid + i * 512];
    }
    if (tid < 128) bs1[tid] = b1[tid];
    wvs[tid] = wv[tid];
    __syncthreads();

    int lane = tid & 63, wid = tid >> 6;
    int l16 = lane & 15, lg = lane >> 4;
    long n0 = (long)blockIdx.x * 128 + wid * 16;
    const unsigned short* Ag = xagg + (n0 + l16) * 64;
    const unsigned short* Ao = xaown + (n0 + l16) * 64;

    f32x4 acc[8];
#pragma unroll
    for (int ot = 0; ot < 8; ++ot) acc[ot] = (f32x4){0.f, 0.f, 0.f, 0.f};

    // ---- MFMA: h1 = relu(A' @ W1'.T + b1) ----
#pragma unroll
    for (int ks = 0; ks < 4; ++ks) {
        int k0 = ks * 32;
        bf16x8 a;
        if (ks < 2) a = *(const bf16x8*)&Ag[k0 + 8 * lg];
        else        a = *(const bf16x8*)&Ao[(k0 - 64) + 8 * lg];
#pragma unroll
        for (int ot = 0; ot < 8; ++ot) {
            int o = ot * 16 + l16;
            bf16x8 b = *(const bf16x8*)&wbuf[(o * 128 + k0 + 8 * lg) ^ ((o & 7) << 3)];
            acc[ot] = __builtin_amdgcn_mfma_f32_16x16x32_bf16(a, b, acc[ot], 0, 0, 0);
        }
    }

    // ---- phase 2 in registers: per row (node) da..dd = relu(h1+b1).wv[0..3] ----
#pragma unroll
    for (int j = 0; j < 4; ++j) {
        float da = 0.f, db = 0.f, dc = 0.f, dd = 0.f;
#pragma unroll
        for (int ot = 0; ot < 8; ++ot) {
            int col = ot * 16 + l16;
            float hv = fmaxf(acc[ot][j] + bs1[col], 0.f);
            da += hv * wvs[col];       db += hv * wvs[128 + col];
            dc += hv * wvs[256 + col]; dd += hv * wvs[384 + col];
        }
        da += __shfl_xor(da, 1, 64); db += __shfl_xor(db, 1, 64);
        dc += __shfl_xor(dc, 1, 64); dd += __shfl_xor(dd, 1, 64);
        da += __shfl_xor(da, 2, 64); db += __shfl_xor(db, 2, 64);
        dc += __shfl_xor(dc, 2, 64); dd += __shfl_xor(dd, 2, 64);
        da += __shfl_xor(da, 4, 64); db += __shfl_xor(db, 4, 64);
        dc += __shfl_xor(dc, 4, 64); dd += __shfl_xor(dd, 4, 64);
        da += __shfl_xor(da, 8, 64); db += __shfl_xor(db, 8, 64);
        dc += __shfl_xor(dc, 8, 64); dd += __shfl_xor(dd, 8, 64);
        long n = n0 + lg * 4 + j;
        if (l16 == 0 && n < N) {
            *(float2*)&ab[n * 2] = make_float2(da, db);
            *(float2*)&cd[n * 2] = make_float2(dc, dd);
        }
    }
}

// ---------------- scalar gather: UV[n] = (mean_nbr a + c[n], mean_nbr b + d[n]) ----------------
__global__ void sgather_kernel(const int* __restrict__ rs, const int* __restrict__ csr,
                               const float* __restrict__ ab, const float* __restrict__ cd,
                               float* __restrict__ UV, long N) {
    long n = (long)blockIdx.x * 256 + threadIdx.x;
    if (n >= N) return;
    int s = rs[n], e = rs[n + 1];
    float sa = 0.f, sb = 0.f;
    int j = s;
    for (; j + 4 <= e; j += 4) {
        unsigned i0 = (unsigned)csr[j] * 2u, i1 = (unsigned)csr[j + 1] * 2u;
        unsigned i2 = (unsigned)csr[j + 2] * 2u, i3 = (unsigned)csr[j + 3] * 2u;
        float2 v0 = *(const float2*)&ab[i0];
        float2 v1 = *(const float2*)&ab[i1];
        float2 v2 = *(const float2*)&ab[i2];
        float2 v3 = *(const float2*)&ab[i3];
        sa += (v0.x + v1.x) + (v2.x + v3.x);
        sb += (v0.y + v1.y) + (v2.y + v3.y);
    }
    for (; j < e; ++j) {
        float2 v = *(const float2*)&ab[(unsigned)csr[j] * 2u];
        sa += v.x; sb += v.y;
    }
    float inv = 1.0f / fmaxf((float)(e - s), 1.0f);
    float2 cdv = *(const float2*)&cd[n * 2];
    *(float2*)&UV[n * 2] = make_float2(sa * inv + cdv.x, sb * inv + cdv.y);
}

// linkpred: out[p] = sigmoid(U[s] + V[d] + C)
__global__ void linkpred_kernel(const void* pairs, const int* flag,
                                const float* __restrict__ UV, const float* __restrict__ wv,
                                float* __restrict__ out, long P) {
    long p = (long)blockIdx.x * 256 + threadIdx.x;
    if (p >= P) return;
    int is64 = *flag;
    long s = load_idx(pairs, 2 * p, is64);
    long d = load_idx(pairs, 2 * p + 1, is64);
    float acc = UV[s * 2] + UV[d * 2 + 1] + wv[512];
    out[p] = 1.0f / (1.0f + expf(-acc));
}

extern "C" void kernel_launch(void* const* d_in, const int* in_sizes, int n_in,
                              void* d_out, int out_size, void* d_ws, size_t ws_size,
                              hipStream_t stream) {
    const float* x    = (const float*)d_in[0];
    const void*  eidx  = d_in[1];
    const void*  pairs = d_in[2];
    const float* W1l = (const float*)d_in[3];
    const float* W1r = (const float*)d_in[4];
    const float* b1  = (const float*)d_in[5];
    const float* W2l = (const float*)d_in[6];
    const float* W2r = (const float*)d_in[7];
    const float* b2  = (const float*)d_in[8];
    const float* Wlp = (const float*)d_in[9];
    const float* blp = (const float*)d_in[10];
    float* out = (float*)d_out;

    long N = in_sizes[0] / 64;
    long E = in_sizes[1] / 2;
    long P = in_sizes[2] / 2;
    long NP = (N + 127) & ~127L;
    int NBK = (int)((N + 255) >> 8);          // <= 512
    int chunk = (int)((E + NBLK_A - 1) / NBLK_A);
    int xcb = (int)((N * 16 + 255) / 256);

    char* w = (char*)d_ws;
    auto alloc = [&](size_t bytes) {
        char* p = w;
        w += (bytes + 255) & ~(size_t)255;
        return p;
    };
    int* row_start = (int*)alloc((N + 1) * sizeof(int));
    int* csr_src   = (int*)alloc(E * sizeof(int));
    int* blk_hist  = (int*)alloc((size_t)NBK * NBLK_A * sizeof(int));
    int* total     = (int*)alloc(NBK * sizeof(int));
    int* base      = (int*)alloc((NBK + 1) * sizeof(int));
    int* flag      = (int*)alloc(64);
    unsigned* ebuf = (unsigned*)alloc(E * sizeof(unsigned));
    unsigned short* xaown = (unsigned short*)alloc((size_t)NP * 64 * 2);
    unsigned short* xagg  = (unsigned short*)alloc((size_t)NP * 64 * 2);
    unsigned short* w1bf  = (unsigned short*)alloc(16384 * 2);
    float* ab = (float*)alloc((size_t)N * 2 * sizeof(float));
    float* cd = (float*)alloc((size_t)N * 2 * sizeof(float));
    float* UV = (float*)alloc((size_t)N * 2 * sizeof(float));
    float* wv = (float*)alloc(1024 * sizeof(float));

    unsigned pre_blocks = (unsigned)(NBLK_A + xcb + 1);
    pre_kernel<<<pre_blocks, 256, 0, stream>>>(eidx, x, W1l, W1r, W2l, W2r, b2, Wlp, blp,
                                               blk_hist, xaown, w1bf, wv, flag,
                                               N, E, NBK, chunk, xcb);

    bucket_relscan_kernel<<<NBK, 256, 0, stream>>>(blk_hist, total);
    base_kernel<<<1, 256, 0, stream>>>(total, base, row_start, NBK, N, E);
    bucket_scatter_kernel<<<NBLK_A, 256, 0, stream>>>(eidx, flag, blk_hist, base, ebuf, E, NBK, chunk);
    bucket_csr_kernel<<<NBK, 256, 0, stream>>>(ebuf, base, csr_src, row_start, N);

    unsigned gth_blocks = (unsigned)((N * 64 + 255) / 256);
    gather_kernel<<<gth_blocks, 256, 0, stream>>>(row_start, csr_src, xaown, xagg, N);

    unsigned gblocks = (unsigned)(NP / 128);
    fused_gemm_kernel<<<gblocks, 512, 0, stream>>>(xagg, xaown, w1bf, b1, wv, ab, cd, N);

    unsigned sgblocks = (unsigned)((N + 255) / 256);
    sgather_kernel<<<sgblocks, 256, 0, stream>>>(row_start, csr_src, ab, cd, UV, N);

    unsigned pblocks = (unsigned)((P + 255) / 256);
    linkpred_kernel<<<pblocks, 256, 0, stream>>>(pairs, flag, UV, wv, out, P);
}